// Round 8
// baseline (393.807 us; speedup 1.0000x reference)
//
#include <hip/hip_runtime.h>
#include <hip/hip_bf16.h>

// Problem: B=4, T=2048, D=1024, H=16, HD=64
#define B_  4
#define T_  2048
#define D_  1024
#define H_  16
#define HD_ 64

typedef short s16x8 __attribute__((ext_vector_type(8)));
typedef short s16x4 __attribute__((ext_vector_type(4)));
typedef float f32x4 __attribute__((ext_vector_type(4)));
typedef unsigned int u32x2 __attribute__((ext_vector_type(2)));

#define MFMA32(a, b, c) __builtin_amdgcn_mfma_f32_16x16x32_bf16(a, b, c, 0, 0, 0)
#define MFMA16(a, b, c) __builtin_amdgcn_mfma_f32_16x16x16bf16_1k(a, b, c, 0, 0, 0)

__device__ __forceinline__ unsigned short f2bf(float f) {
  unsigned u = __builtin_bit_cast(unsigned, f);
  u += 0x7fffu + ((u >> 16) & 1u);   // RNE
  return (unsigned short)(u >> 16);
}

__device__ __forceinline__ float bf2f(unsigned short h) {
  return __builtin_bit_cast(float, (unsigned)h << 16);
}

#define GLOAD_LDS16(src, dst)                                            \
  __builtin_amdgcn_global_load_lds(                                      \
      (__attribute__((address_space(1))) void*)(void*)(src),             \
      (__attribute__((address_space(3))) void*)(dst), 16, 0, 0)

// ---------------------------------------------------------------- convert x
__global__ __launch_bounds__(256) void convert_x_kernel(
    const float* __restrict__ in, unsigned short* __restrict__ out, int n8) {
  int i = blockIdx.x * 256 + threadIdx.x;
  if (i >= n8) return;
  const float4* p = ((const float4*)in) + (size_t)i * 2;
  float4 a = p[0], b = p[1];
  s16x8 o;
  o[0] = (short)f2bf(a.x); o[1] = (short)f2bf(a.y);
  o[2] = (short)f2bf(a.z); o[3] = (short)f2bf(a.w);
  o[4] = (short)f2bf(b.x); o[5] = (short)f2bf(b.y);
  o[6] = (short)f2bf(b.z); o[7] = (short)f2bf(b.w);
  *(((s16x8*)out) + i) = o;
}

// ------------------------------------------------- transpose W [K][N] -> bf16 [N][K]
__global__ __launch_bounds__(256) void transpose_w_kernel(
    const float* __restrict__ W, unsigned short* __restrict__ Wt, int K, int N) {
  __shared__ float tile[32][33];
  int n0 = blockIdx.x * 32, k0 = blockIdx.y * 32;
  int tx = threadIdx.x & 31, ty = threadIdx.x >> 5;  // ty 0..7
#pragma unroll
  for (int j = 0; j < 4; ++j) {
    int k = ty + j * 8;
    tile[k][tx] = W[(size_t)(k0 + k) * N + n0 + tx];
  }
  __syncthreads();
#pragma unroll
  for (int j = 0; j < 4; ++j) {
    int n = ty + j * 8;
    Wt[(size_t)(n0 + n) * K + k0 + tx] = f2bf(tile[tx][n]);
  }
}

// ---------------------------------------------------------------- GEMM 128x128
// m97-structure: linear LDS, global_load_lds w=16, no swizzle.
// C[M,N] = A[M,K] * Bt[N,K]^T + bias ; A,Bt bf16 ; OUTF32 ? f32 : bf16 out
template <int OUTF32>
__global__ __launch_bounds__(256) void gemm_kernel(
    const unsigned short* __restrict__ A, const unsigned short* __restrict__ Bt,
    const float* __restrict__ bias, void* __restrict__ Cout, int M, int N, int K) {
  __shared__ char lds[32768];
  char* Al = lds;
  char* Bl = lds + 16384;
  const int n0 = blockIdx.x * 128, m0 = blockIdx.y * 128;
  const int w = threadIdx.x >> 6, lane = threadIdx.x & 63;
  const int l15 = lane & 15, g = lane >> 4;
  const int wr = w >> 1, wc = w & 1;
  const int srow = (lane >> 3);       // 0..7 within chunk
  const int u = lane & 7;             // d-octet 0..7
  f32x4 acc[4][4] = {};

  for (int kt = 0; kt < K; kt += 64) {
    __syncthreads();
#pragma unroll
    for (int i = 0; i < 4; ++i) {
      int c = w * 4 + i;              // chunk 0..15, 8 rows each
      int row = c * 8 + srow;         // 0..127
      const unsigned short* srcA = A + (size_t)(m0 + row) * K + kt + u * 8;
      GLOAD_LDS16(srcA, Al + c * 1024);
      const unsigned short* srcB = Bt + (size_t)(n0 + row) * K + kt + u * 8;
      GLOAD_LDS16(srcB, Bl + c * 1024);
    }
    __syncthreads();
#pragma unroll
    for (int kk = 0; kk < 2; ++kk) {
      s16x8 af[4], bfr[4];
#pragma unroll
      for (int mi = 0; mi < 4; ++mi) {
        int row = wr * 64 + mi * 16 + l15;
        af[mi] = *(const s16x8*)(Al + row * 128 + kk * 64 + g * 16);
      }
#pragma unroll
      for (int ni = 0; ni < 4; ++ni) {
        int row = wc * 64 + ni * 16 + l15;
        bfr[ni] = *(const s16x8*)(Bl + row * 128 + kk * 64 + g * 16);
      }
#pragma unroll
      for (int mi = 0; mi < 4; ++mi)
#pragma unroll
        for (int ni = 0; ni < 4; ++ni)
          acc[mi][ni] = MFMA32(af[mi], bfr[ni], acc[mi][ni]);
    }
  }
  // epilogue: D layout col=lane&15, row=(lane>>4)*4+r
#pragma unroll
  for (int ni = 0; ni < 4; ++ni) {
    int col = n0 + wc * 64 + ni * 16 + l15;
    float bv = bias[col];
#pragma unroll
    for (int mi = 0; mi < 4; ++mi) {
      int row = m0 + wr * 64 + mi * 16 + g * 4;
#pragma unroll
      for (int r = 0; r < 4; ++r) {
        float v = acc[mi][ni][r] + bv;
        if (OUTF32)
          ((float*)Cout)[(size_t)(row + r) * N + col] = v;
        else
          ((unsigned short*)Cout)[(size_t)(row + r) * N + col] = f2bf(v);
      }
    }
  }
}

// ---------------------------------------------------------------- attention
// QBLK=128, 8 waves (512 thr), grid (8, B*H) = 512 blocks = 2/CU exactly.
// Block bx processes q-tiles {15-bx, bx} sequentially (34 balanced kv-iters).
// Wave w owns q rows [qt*128+16w, +16). Swapped QK^T: S^T = mfma(A=K, B=Q).
// K: reg-staged, octet-XOR-swizzled ds_write_b128/ds_read_b128 (r4/r5-valid).
// V: reg-staged TRANSPOSED scatter into Vt[d][key] stride 66 (r5-validated
// mechanism; 2-way write banks); PV A-frag = natural ds_read_b64.
// T13 defer-max, T14 reg prefetch, tree max-reduce, fully-masked-wave skip.
#define VT_STR 66
__global__ __launch_bounds__(512, 4) void attn_kernel(
    const unsigned short* __restrict__ qkv, unsigned short* __restrict__ yatt) {
  __shared__ char lds[16640];  // K 8192 | Vt 64*66*2=8448 ; aliased by ylds[64][130]
  const int bx = blockIdx.x;          // 0..7
  const int bh = blockIdx.y;
  const int b = bh >> 4, h = bh & 15;
  const int tid = threadIdx.x;
  const int w = tid >> 6;
  const int lane = tid & 63;
  const int l15 = lane & 15, g = lane >> 4;

  const size_t rowstride = 3 * D_;  // 3072 elems per token row
  const unsigned short* Qb = qkv + (size_t)b * T_ * rowstride + h * HD_;
  const unsigned short* Kb = Qb + D_;
  const unsigned short* Vb = Qb + 2 * D_;

  char* Klds = lds;
  unsigned short* Vt = (unsigned short*)(lds + 8192);  // [64 d][66]

  // staging indices: row = tid>>3 (0..63), oct = tid&7 for both K and V
  const int srow = tid >> 3;
  const int oct = tid & 7;
  // loop-invariant swizzled K-read octet offsets (key&7 == l15&7)
  const int koff0 = (g ^ (l15 & 7)) << 4;
  const int koff1 = ((4 + g) ^ (l15 & 7)) << 4;
  const float SC = 0.18033688011112042f;  // log2(e)/sqrt(64)

  s16x8 kreg, vreg;
  auto load_kv = [&](int kt) {
    kreg = *(const s16x8*)(Kb + (size_t)(kt * 64 + srow) * rowstride + oct * 8);
    vreg = *(const s16x8*)(Vb + (size_t)(kt * 64 + srow) * rowstride + oct * 8);
  };

  load_kv(0);
#pragma unroll 1
  for (int ti = 0; ti < 2; ++ti) {
    const int qt = ti ? bx : 15 - bx;
    // Q fragments with SC pre-folded (B operand: col=l15 -> q row, k=g*8+j -> d)
    s16x8 qf0, qf1;
    {
      const unsigned short* qr = Qb + (size_t)(qt * 128 + w * 16 + l15) * rowstride;
      s16x8 a0 = *(const s16x8*)(qr + g * 8);
      s16x8 a1 = *(const s16x8*)(qr + 32 + g * 8);
#pragma unroll
      for (int j = 0; j < 8; ++j) {
        qf0[j] = (short)f2bf(bf2f((unsigned short)a0[j]) * SC);
        qf1[j] = (short)f2bf(bf2f((unsigned short)a1[j]) * SC);
      }
    }
    float m = -1e30f, rs = 0.f;
    f32x4 acc[4] = {};  // y^T: acc[db] holds d = db*16 + g*4 + r, q col = l15
    const int ktmax = 2 * qt + 1;

#pragma unroll 1
    for (int kt = 0; kt <= ktmax; ++kt) {
      __syncthreads();  // LDS free (prev compute / epilogue done)
      // K: octet-XOR-swizzled write (reader applies same XOR -> identity)
      *(s16x8*)(Klds + srow * 128 + ((oct ^ (srow & 7)) << 4)) = kreg;
      // V^T scatter: Vt[d = oct*8+j][key = srow]
#pragma unroll
      for (int j = 0; j < 8; ++j)
        Vt[(oct * 8 + j) * VT_STR + srow] = (unsigned short)vreg[j];
      __syncthreads();
      // T14: prefetch next K/V into regs -> latency hides under compute
      if (kt < ktmax) load_kv(kt + 1);
      else if (ti == 0) load_kv(0);

      const bool skip = (kt * 64 > qt * 128 + w * 16 + 15);  // fully-masked wave
      if (!skip) {
        // QK^T
        float tv[16];
        const char* kbase = Klds + l15 * 128;
#pragma unroll
        for (int kk = 0; kk < 4; ++kk) {
          const s16x8 kf0 = *(const s16x8*)(kbase + kk * 2048 + koff0);
          const s16x8 kf1 = *(const s16x8*)(kbase + kk * 2048 + koff1);
          f32x4 s = {};
          s = MFMA32(kf0, qf0, s);
          s = MFMA32(kf1, qf1, s);
#pragma unroll
          for (int r = 0; r < 4; ++r) tv[kk * 4 + r] = s[r];
        }
        if (kt * 64 + 63 > qt * 128 + w * 16) {  // diagonal: causal mask
          int q = qt * 128 + w * 16 + l15;
#pragma unroll
          for (int kk = 0; kk < 4; ++kk)
#pragma unroll
            for (int r = 0; r < 4; ++r)
              if (kt * 64 + kk * 16 + g * 4 + r > q) tv[kk * 4 + r] = -1e30f;
        }
        // tree max-reduce (depth 4) + cross-lane
        float x0 = fmaxf(tv[0], tv[1]), x1 = fmaxf(tv[2], tv[3]);
        float x2 = fmaxf(tv[4], tv[5]), x3 = fmaxf(tv[6], tv[7]);
        float x4 = fmaxf(tv[8], tv[9]), x5 = fmaxf(tv[10], tv[11]);
        float x6 = fmaxf(tv[12], tv[13]), x7 = fmaxf(tv[14], tv[15]);
        float y0 = fmaxf(fmaxf(x0, x1), fmaxf(x2, x3));
        float y1 = fmaxf(fmaxf(x4, x5), fmaxf(x6, x7));
        float tm = fmaxf(y0, y1);
        tm = fmaxf(tm, __shfl_xor(tm, 16));
        tm = fmaxf(tm, __shfl_xor(tm, 32));
        if (!__all(tm - m <= 8.0f)) {  // T13 defer-max: P bounded by 2^8
          float mn = fmaxf(m, tm);
          float corr = exp2f(m - mn);
          m = mn;
          rs *= corr;
#pragma unroll
          for (int i = 0; i < 4; ++i) {
            acc[i][0] *= corr; acc[i][1] *= corr;
            acc[i][2] *= corr; acc[i][3] *= corr;
          }
        }
        s16x4 pb[4];
        float ps = 0.f;
#pragma unroll
        for (int kk = 0; kk < 4; ++kk) {
          float p0 = exp2f(tv[kk * 4 + 0] - m), p1 = exp2f(tv[kk * 4 + 1] - m);
          float p2 = exp2f(tv[kk * 4 + 2] - m), p3 = exp2f(tv[kk * 4 + 3] - m);
          ps += (p0 + p1) + (p2 + p3);
          u32x2 pk;  // truncation-pack two hi16s per v_perm
          pk[0] = __builtin_amdgcn_perm(__builtin_bit_cast(unsigned, p1),
                                        __builtin_bit_cast(unsigned, p0), 0x07060302u);
          pk[1] = __builtin_amdgcn_perm(__builtin_bit_cast(unsigned, p3),
                                        __builtin_bit_cast(unsigned, p2), 0x07060302u);
          pb[kk] = __builtin_bit_cast(s16x4, pk);
        }
        rs += ps;
        // PV: y^T += mfma(A = Vt fragment, B = P^T)
#pragma unroll
        for (int kk = 0; kk < 4; ++kk) {
#pragma unroll
          for (int db = 0; db < 4; ++db) {
            s16x4 vf =
                *(const s16x4*)(Vt + (db * 16 + l15) * VT_STR + kk * 16 + g * 4);
            acc[db] = MFMA16(vf, pb[kk], acc[db]);
          }
        }
      }
    }

    // epilogue: denom + transpose y^T -> y via ylds (aliases K/Vt), store
    float rtot = rs + __shfl_xor(rs, 16);
    rtot += __shfl_xor(rtot, 32);
    float inv = 1.0f / rtot;
    __syncthreads();  // everyone done reading K/Vt
    unsigned short* ylds = (unsigned short*)lds;  // [64 d][130]
#pragma unroll
    for (int db = 0; db < 4; ++db)
#pragma unroll
      for (int r = 0; r < 4; ++r)
        ylds[(db * 16 + g * 4 + r) * 130 + w * 16 + l15] = f2bf(acc[db][r] * inv);
    __syncthreads();
    {
      int qq = tid >> 2;                 // 0..127
      int dc = (tid & 3) * 16;
      s16x8 o1, o2;
#pragma unroll
      for (int j = 0; j < 8; ++j) {
        o1[j] = (short)ylds[(dc + j) * 130 + qq];
        o2[j] = (short)ylds[(dc + 8 + j) * 130 + qq];
      }
      unsigned short* dst =
          yatt + (size_t)(b * T_ + qt * 128 + qq) * D_ + h * HD_ + dc;
      *(s16x8*)(dst) = o1;
      *(s16x8*)(dst + 8) = o2;
    }
  }
}

// ---------------------------------------------------------------- launcher
extern "C" void kernel_launch(void* const* d_in, const int* in_sizes, int n_in,
                              void* d_out, int out_size, void* d_ws, size_t ws_size,
                              hipStream_t stream) {
  const float* x     = (const float*)d_in[0];
  const float* Wqkv  = (const float*)d_in[1];
  const float* bqkv  = (const float*)d_in[2];
  const float* Wproj = (const float*)d_in[3];
  const float* bproj = (const float*)d_in[4];
  float* out = (float*)d_out;

  // workspace layout (bf16 buffers), 72 MiB total; yb aliases xb (dead after gemm<0>)
  unsigned short* xb   = (unsigned short*)d_ws;              // [8192][1024]
  unsigned short* Wqb  = xb + (size_t)8192 * 1024;           // [3072][1024] (W_qkv^T)
  unsigned short* Wpb  = Wqb + (size_t)3072 * 1024;          // [1024][1024] (W_proj^T)
  unsigned short* qkvb = Wpb + (size_t)1024 * 1024;          // [8192][3072]
  unsigned short* yb   = xb;                                 // alias: x dead after gemm<0>

  convert_x_kernel<<<dim3(4096), dim3(256), 0, stream>>>(x, xb, 8192 * 1024 / 8);
  transpose_w_kernel<<<dim3(96, 32), dim3(256), 0, stream>>>(Wqkv, Wqb, 1024, 3072);
  transpose_w_kernel<<<dim3(32, 32), dim3(256), 0, stream>>>(Wproj, Wpb, 1024, 1024);
  gemm_kernel<0><<<dim3(24, 64), dim3(256), 0, stream>>>(xb, Wqb, bqkv, qkvb, 8192, 3072, 1024);
  attn_kernel<<<dim3(8, 64), dim3(512), 0, stream>>>(qkvb, yb);
  gemm_kernel<1><<<dim3(8, 64), dim3(256), 0, stream>>>(yb, Wpb, bproj, out, 8192, 1024, 1024);
}

// Round 9
// 210.843 us; speedup vs baseline: 1.8678x; 1.8678x over previous
//
#include <hip/hip_runtime.h>
#include <hip/hip_bf16.h>

// Problem: B=4, T=2048, D=1024, H=16, HD=64
#define B_  4
#define T_  2048
#define D_  1024
#define H_  16
#define HD_ 64

typedef short s16x8 __attribute__((ext_vector_type(8)));
typedef short s16x4 __attribute__((ext_vector_type(4)));
typedef float f32x4 __attribute__((ext_vector_type(4)));
typedef unsigned int u32x2 __attribute__((ext_vector_type(2)));

#define MFMA32(a, b, c) __builtin_amdgcn_mfma_f32_16x16x32_bf16(a, b, c, 0, 0, 0)
#define MFMA16(a, b, c) __builtin_amdgcn_mfma_f32_16x16x16bf16_1k(a, b, c, 0, 0, 0)

__device__ __forceinline__ unsigned short f2bf(float f) {
  unsigned u = __builtin_bit_cast(unsigned, f);
  u += 0x7fffu + ((u >> 16) & 1u);   // RNE
  return (unsigned short)(u >> 16);
}

__device__ __forceinline__ float bf2f(unsigned short h) {
  return __builtin_bit_cast(float, (unsigned)h << 16);
}

#define GLOAD_LDS16(src, dst)                                            \
  __builtin_amdgcn_global_load_lds(                                      \
      (__attribute__((address_space(1))) void*)(void*)(src),             \
      (__attribute__((address_space(3))) void*)(dst), 16, 0, 0)

// ---------------------------------------------------------------- convert x
__global__ __launch_bounds__(256) void convert_x_kernel(
    const float* __restrict__ in, unsigned short* __restrict__ out, int n8) {
  int i = blockIdx.x * 256 + threadIdx.x;
  if (i >= n8) return;
  const float4* p = ((const float4*)in) + (size_t)i * 2;
  float4 a = p[0], b = p[1];
  s16x8 o;
  o[0] = (short)f2bf(a.x); o[1] = (short)f2bf(a.y);
  o[2] = (short)f2bf(a.z); o[3] = (short)f2bf(a.w);
  o[4] = (short)f2bf(b.x); o[5] = (short)f2bf(b.y);
  o[6] = (short)f2bf(b.z); o[7] = (short)f2bf(b.w);
  *(((s16x8*)out) + i) = o;
}

// ------------------------------------------------- transpose W [K][N] -> bf16 [N][K]
__global__ __launch_bounds__(256) void transpose_w_kernel(
    const float* __restrict__ W, unsigned short* __restrict__ Wt, int K, int N) {
  __shared__ float tile[32][33];
  int n0 = blockIdx.x * 32, k0 = blockIdx.y * 32;
  int tx = threadIdx.x & 31, ty = threadIdx.x >> 5;  // ty 0..7
#pragma unroll
  for (int j = 0; j < 4; ++j) {
    int k = ty + j * 8;
    tile[k][tx] = W[(size_t)(k0 + k) * N + n0 + tx];
  }
  __syncthreads();
#pragma unroll
  for (int j = 0; j < 4; ++j) {
    int n = ty + j * 8;
    Wt[(size_t)(n0 + n) * K + k0 + tx] = f2bf(tile[tx][n]);
  }
}

// ---------------------------------------------------------------- GEMM 128x128
// m97-structure: linear LDS, global_load_lds w=16, no swizzle.
// C[M,N] = A[M,K] * Bt[N,K]^T + bias ; A,Bt bf16 ; OUTF32 ? f32 : bf16 out
template <int OUTF32>
__global__ __launch_bounds__(256) void gemm_kernel(
    const unsigned short* __restrict__ A, const unsigned short* __restrict__ Bt,
    const float* __restrict__ bias, void* __restrict__ Cout, int M, int N, int K) {
  __shared__ char lds[32768];
  char* Al = lds;
  char* Bl = lds + 16384;
  const int n0 = blockIdx.x * 128, m0 = blockIdx.y * 128;
  const int w = threadIdx.x >> 6, lane = threadIdx.x & 63;
  const int l15 = lane & 15, g = lane >> 4;
  const int wr = w >> 1, wc = w & 1;
  const int srow = (lane >> 3);       // 0..7 within chunk
  const int u = lane & 7;             // d-octet 0..7
  f32x4 acc[4][4] = {};

  for (int kt = 0; kt < K; kt += 64) {
    __syncthreads();
#pragma unroll
    for (int i = 0; i < 4; ++i) {
      int c = w * 4 + i;              // chunk 0..15, 8 rows each
      int row = c * 8 + srow;         // 0..127
      const unsigned short* srcA = A + (size_t)(m0 + row) * K + kt + u * 8;
      GLOAD_LDS16(srcA, Al + c * 1024);
      const unsigned short* srcB = Bt + (size_t)(n0 + row) * K + kt + u * 8;
      GLOAD_LDS16(srcB, Bl + c * 1024);
    }
    __syncthreads();
#pragma unroll
    for (int kk = 0; kk < 2; ++kk) {
      s16x8 af[4], bfr[4];
#pragma unroll
      for (int mi = 0; mi < 4; ++mi) {
        int row = wr * 64 + mi * 16 + l15;
        af[mi] = *(const s16x8*)(Al + row * 128 + kk * 64 + g * 16);
      }
#pragma unroll
      for (int ni = 0; ni < 4; ++ni) {
        int row = wc * 64 + ni * 16 + l15;
        bfr[ni] = *(const s16x8*)(Bl + row * 128 + kk * 64 + g * 16);
      }
#pragma unroll
      for (int mi = 0; mi < 4; ++mi)
#pragma unroll
        for (int ni = 0; ni < 4; ++ni)
          acc[mi][ni] = MFMA32(af[mi], bfr[ni], acc[mi][ni]);
    }
  }
  // epilogue: D layout col=lane&15, row=(lane>>4)*4+r
#pragma unroll
  for (int ni = 0; ni < 4; ++ni) {
    int col = n0 + wc * 64 + ni * 16 + l15;
    float bv = bias[col];
#pragma unroll
    for (int mi = 0; mi < 4; ++mi) {
      int row = m0 + wr * 64 + mi * 16 + g * 4;
#pragma unroll
      for (int r = 0; r < 4; ++r) {
        float v = acc[mi][ni][r] + bv;
        if (OUTF32)
          ((float*)Cout)[(size_t)(row + r) * N + col] = v;
        else
          ((unsigned short*)Cout)[(size_t)(row + r) * N + col] = f2bf(v);
      }
    }
  }
}

// ---------------------------------------------------------------- attention
// r5-validated structure: QBLK=64, 4 waves, grid (16, B*H) = 1024 blocks =
// 4/CU; block bx processes q-tiles {31-bx, bx} sequentially (33 kv-iters).
// Swapped QK^T: S^T = mfma(A=K, B=Q) -> lane holds keys (g*4+r), q col = l15.
// K: octet-XOR-swizzled ds_write_b128/ds_read_b128. V^T: block-padded scatter.
// NEW vs r5: (1) 2-deep K/V register prefetch over a flat 33-iter schedule
// (cur/nxt named slots, rotate by mov -- static indexing, rule #20);
// (2) s_setprio(1) around MFMA clusters (T5, attn-validated).
__global__ __launch_bounds__(256, 4) void attn_kernel(
    const unsigned short* __restrict__ qkv, unsigned short* __restrict__ yatt) {
  __shared__ char lds[8192 + 9344];  // K 8KB swizzled + Vt 4*1168*2B; reused for y
  const int bx = blockIdx.x;          // 0..15
  const int bh = blockIdx.y;
  const int b = bh >> 4, h = bh & 15;
  const int w = threadIdx.x >> 6;
  const int lane = threadIdx.x & 63;
  const int l15 = lane & 15, g = lane >> 4;

  const size_t rowstride = 3 * D_;  // 3072 elems per token row
  const unsigned short* Qb = qkv + (size_t)b * T_ * rowstride + h * HD_;
  const unsigned short* Kb = Qb + D_;
  const unsigned short* Vb = Qb + 2 * D_;

  char* Klds = lds;
  unsigned short* Vt = (unsigned short*)(lds + 8192);  // [4 blk][16 d][72 key]+pad

  const int krow0 = (w * 2 + 0) * 8 + (lane >> 3);
  const int krow1 = (w * 2 + 1) * 8 + (lane >> 3);
  const int u = lane & 7;
  const int vkey = w * 16 + (lane >> 2);
  const int vdb = lane & 3;
  const float SC = 0.18033688011112042f;  // log2(e)/sqrt(64)

  const int qtA = 31 - bx;            // first (long) tile; nA = qtA+1 >= 17
  const int nA = qtA + 1;

  // 2-deep prefetch slots (named; rotated by mov -- no runtime indexing)
  s16x8 kc0, kc1, vc0, vc1;  // cur: staged this iter
  s16x8 kn0, kn1, vn0, vn1;  // nxt: staged next iter

  auto ld = [&](int kt, s16x8& a, s16x8& b2, s16x8& c, s16x8& d2) {
    const unsigned short* kb = Kb + (size_t)(kt * 64) * rowstride;
    a = *(const s16x8*)(kb + (size_t)krow0 * rowstride + u * 8);
    b2 = *(const s16x8*)(kb + (size_t)krow1 * rowstride + u * 8);
    const unsigned short* vs = Vb + (size_t)(kt * 64 + vkey) * rowstride + vdb * 16;
    c = *(const s16x8*)(vs);
    d2 = *(const s16x8*)(vs + 8);
  };

  ld(0, kc0, kc1, vc0, vc1);
  ld(1, kn0, kn1, vn0, vn1);  // flat index 1 (nA >= 17 so this is tile A, kt=1)
  int f = 0;                  // flat kv-iter counter, 0..32

#pragma unroll 1
  for (int ti = 0; ti < 2; ++ti) {
    const int qt = ti ? bx : qtA;
    // Q fragments with SC pre-folded (B operand: col=l15 -> q row, k=g*8+j -> d)
    s16x8 qf0, qf1;
    {
      const unsigned short* qr = Qb + (size_t)(qt * 64 + w * 16 + l15) * rowstride;
      s16x8 a0 = *(const s16x8*)(qr + g * 8);
      s16x8 a1 = *(const s16x8*)(qr + 32 + g * 8);
#pragma unroll
      for (int j = 0; j < 8; ++j) {
        qf0[j] = (short)f2bf(bf2f((unsigned short)a0[j]) * SC);
        qf1[j] = (short)f2bf(bf2f((unsigned short)a1[j]) * SC);
      }
    }
    float m = -1e30f, rs = 0.f;
    f32x4 acc[4] = {};  // y^T: acc[db] holds d = db*16 + g*4 + r, q col = l15

#pragma unroll 1
    for (int kt = 0; kt <= qt; ++kt) {
      __syncthreads();
      // K: octet-XOR-swizzled write (reader applies same XOR -> identity)
      *(s16x8*)(Klds + krow0 * 128 + ((u ^ (krow0 & 7)) << 4)) = kc0;
      *(s16x8*)(Klds + krow1 * 128 + ((u ^ (krow1 & 7)) << 4)) = kc1;
      // V^T: block-padded layout, conflict-free writes
#pragma unroll
      for (int j = 0; j < 8; ++j) {
        Vt[vdb * 1168 + j * 72 + vkey] = (unsigned short)vc0[j];
        Vt[vdb * 1168 + (8 + j) * 72 + vkey] = (unsigned short)vc1[j];
      }
      __syncthreads();
      // rotate slots and issue the f+2 load (2-deep: ~1.5-2 iters in flight)
      kc0 = kn0; kc1 = kn1; vc0 = vn0; vc1 = vn1;
      {
        int f2 = f + 2;
        if (f2 < 33) {
          int kt2 = (f2 < nA) ? f2 : f2 - nA;
          ld(kt2, kn0, kn1, vn0, vn1);
        }
      }

      // QK^T
      float tv[16];
      __builtin_amdgcn_s_setprio(1);
#pragma unroll
      for (int kk = 0; kk < 4; ++kk) {
        int key = kk * 16 + l15;
        const s16x8 kf0 = *(const s16x8*)(Klds + key * 128 + ((g ^ (key & 7)) << 4));
        const s16x8 kf1 = *(const s16x8*)(Klds + key * 128 + (((4 + g) ^ (key & 7)) << 4));
        f32x4 s = {};
        s = MFMA32(kf0, qf0, s);
        s = MFMA32(kf1, qf1, s);
#pragma unroll
        for (int r = 0; r < 4; ++r) tv[kk * 4 + r] = s[r];
      }
      __builtin_amdgcn_s_setprio(0);
      if (kt == qt) {  // diagonal tile: causal mask
        int q = qt * 64 + w * 16 + l15;
#pragma unroll
        for (int kk = 0; kk < 4; ++kk)
#pragma unroll
          for (int r = 0; r < 4; ++r)
            if (kt * 64 + kk * 16 + g * 4 + r > q) tv[kk * 4 + r] = -1e30f;
      }
      // tree max-reduce + cross-lane
      float x0 = fmaxf(tv[0], tv[1]), x1 = fmaxf(tv[2], tv[3]);
      float x2 = fmaxf(tv[4], tv[5]), x3 = fmaxf(tv[6], tv[7]);
      float x4 = fmaxf(tv[8], tv[9]), x5 = fmaxf(tv[10], tv[11]);
      float x6 = fmaxf(tv[12], tv[13]), x7 = fmaxf(tv[14], tv[15]);
      float tm = fmaxf(fmaxf(fmaxf(x0, x1), fmaxf(x2, x3)),
                       fmaxf(fmaxf(x4, x5), fmaxf(x6, x7)));
      tm = fmaxf(tm, __shfl_xor(tm, 16));
      tm = fmaxf(tm, __shfl_xor(tm, 32));
      if (!__all(tm - m <= 8.0f)) {  // T13 defer-max: P bounded by 2^8
        float mn = fmaxf(m, tm);
        float corr = exp2f(m - mn);
        m = mn;
        rs *= corr;
#pragma unroll
        for (int i = 0; i < 4; ++i) {
          acc[i][0] *= corr; acc[i][1] *= corr;
          acc[i][2] *= corr; acc[i][3] *= corr;
        }
      }
      s16x4 pb[4];
      float ps = 0.f;
#pragma unroll
      for (int kk = 0; kk < 4; ++kk) {
        float p0 = exp2f(tv[kk * 4 + 0] - m), p1 = exp2f(tv[kk * 4 + 1] - m);
        float p2 = exp2f(tv[kk * 4 + 2] - m), p3 = exp2f(tv[kk * 4 + 3] - m);
        ps += (p0 + p1) + (p2 + p3);
        u32x2 pk;  // truncation-pack two hi16s per v_perm
        pk[0] = __builtin_amdgcn_perm(__builtin_bit_cast(unsigned, p1),
                                      __builtin_bit_cast(unsigned, p0), 0x07060302u);
        pk[1] = __builtin_amdgcn_perm(__builtin_bit_cast(unsigned, p3),
                                      __builtin_bit_cast(unsigned, p2), 0x07060302u);
        pb[kk] = __builtin_bit_cast(s16x4, pk);
      }
      rs += ps;
      // PV: y^T += mfma(A = Vt fragment, B = P^T)
      __builtin_amdgcn_s_setprio(1);
#pragma unroll
      for (int kk = 0; kk < 4; ++kk) {
#pragma unroll
        for (int db = 0; db < 4; ++db) {
          s16x4 vf = *(const s16x4*)(Vt + db * 1168 + l15 * 72 + kk * 16 + g * 4);
          acc[db] = MFMA16(vf, pb[kk], acc[db]);
        }
      }
      __builtin_amdgcn_s_setprio(0);
      ++f;
    }

    // epilogue for this tile: denom + transpose y^T -> y via LDS, bf16 store
    float rtot = rs + __shfl_xor(rs, 16);
    rtot += __shfl_xor(rtot, 32);
    float inv = 1.0f / rtot;
    __syncthreads();
    unsigned short* ylds = (unsigned short*)lds;  // [64 d][66]
#pragma unroll
    for (int db = 0; db < 4; ++db)
#pragma unroll
      for (int r = 0; r < 4; ++r)
        ylds[(db * 16 + g * 4 + r) * 66 + w * 16 + l15] = f2bf(acc[db][r] * inv);
    __syncthreads();
    int qq = threadIdx.x >> 2;
    int dc = (threadIdx.x & 3) * 16;
    s16x8 o1, o2;
#pragma unroll
    for (int j = 0; j < 8; ++j) {
      o1[j] = (short)ylds[(dc + j) * 66 + qq];
      o2[j] = (short)ylds[(dc + 8 + j) * 66 + qq];
    }
    unsigned short* dst = yatt + (size_t)(b * T_ + qt * 64 + qq) * D_ + h * HD_ + dc;
    *(s16x8*)(dst) = o1;
    *(s16x8*)(dst + 8) = o2;
  }
}

// ---------------------------------------------------------------- launcher
extern "C" void kernel_launch(void* const* d_in, const int* in_sizes, int n_in,
                              void* d_out, int out_size, void* d_ws, size_t ws_size,
                              hipStream_t stream) {
  const float* x     = (const float*)d_in[0];
  const float* Wqkv  = (const float*)d_in[1];
  const float* bqkv  = (const float*)d_in[2];
  const float* Wproj = (const float*)d_in[3];
  const float* bproj = (const float*)d_in[4];
  float* out = (float*)d_out;

  // workspace layout (bf16 buffers), 72 MiB total; yb aliases xb (dead after gemm<0>)
  unsigned short* xb   = (unsigned short*)d_ws;              // [8192][1024]
  unsigned short* Wqb  = xb + (size_t)8192 * 1024;           // [3072][1024] (W_qkv^T)
  unsigned short* Wpb  = Wqb + (size_t)3072 * 1024;          // [1024][1024] (W_proj^T)
  unsigned short* qkvb = Wpb + (size_t)1024 * 1024;          // [8192][3072]
  unsigned short* yb   = xb;                                 // alias: x dead after gemm<0>

  convert_x_kernel<<<dim3(4096), dim3(256), 0, stream>>>(x, xb, 8192 * 1024 / 8);
  transpose_w_kernel<<<dim3(96, 32), dim3(256), 0, stream>>>(Wqkv, Wqb, 1024, 3072);
  transpose_w_kernel<<<dim3(32, 32), dim3(256), 0, stream>>>(Wproj, Wpb, 1024, 1024);
  gemm_kernel<0><<<dim3(24, 64), dim3(256), 0, stream>>>(xb, Wqb, bqkv, qkvb, 8192, 3072, 1024);
  attn_kernel<<<dim3(16, 64), dim3(256), 0, stream>>>(qkvb, yb);
  gemm_kernel<1><<<dim3(8, 64), dim3(256), 0, stream>>>(yb, Wpb, bproj, out, 8192, 1024, 1024);
}

// Round 10
// 207.377 us; speedup vs baseline: 1.8990x; 1.0167x over previous
//
#include <hip/hip_runtime.h>
#include <hip/hip_bf16.h>

// Problem: B=4, T=2048, D=1024, H=16, HD=64
#define B_  4
#define T_  2048
#define D_  1024
#define H_  16
#define HD_ 64

typedef short s16x8 __attribute__((ext_vector_type(8)));
typedef short s16x4 __attribute__((ext_vector_type(4)));
typedef float f32x4 __attribute__((ext_vector_type(4)));
typedef unsigned int u32x2 __attribute__((ext_vector_type(2)));

#define MFMA32(a, b, c) __builtin_amdgcn_mfma_f32_16x16x32_bf16(a, b, c, 0, 0, 0)
#define MFMA16(a, b, c) __builtin_amdgcn_mfma_f32_16x16x16bf16_1k(a, b, c, 0, 0, 0)

__device__ __forceinline__ unsigned short f2bf(float f) {
  unsigned u = __builtin_bit_cast(unsigned, f);
  u += 0x7fffu + ((u >> 16) & 1u);   // RNE
  return (unsigned short)(u >> 16);
}

__device__ __forceinline__ float bf2f(unsigned short h) {
  return __builtin_bit_cast(float, (unsigned)h << 16);
}

#define GLOAD_LDS16(src, dst)                                            \
  __builtin_amdgcn_global_load_lds(                                      \
      (__attribute__((address_space(1))) void*)(void*)(src),             \
      (__attribute__((address_space(3))) void*)(dst), 16, 0, 0)

// ---------------------------------------------------------------- convert x
__global__ __launch_bounds__(256) void convert_x_kernel(
    const float* __restrict__ in, unsigned short* __restrict__ out, int n8) {
  int i = blockIdx.x * 256 + threadIdx.x;
  if (i >= n8) return;
  const float4* p = ((const float4*)in) + (size_t)i * 2;
  float4 a = p[0], b = p[1];
  s16x8 o;
  o[0] = (short)f2bf(a.x); o[1] = (short)f2bf(a.y);
  o[2] = (short)f2bf(a.z); o[3] = (short)f2bf(a.w);
  o[4] = (short)f2bf(b.x); o[5] = (short)f2bf(b.y);
  o[6] = (short)f2bf(b.z); o[7] = (short)f2bf(b.w);
  *(((s16x8*)out) + i) = o;
}

// ------------------------------------------------- transpose W [K][N] -> bf16 [N][K]
__global__ __launch_bounds__(256) void transpose_w_kernel(
    const float* __restrict__ W, unsigned short* __restrict__ Wt, int K, int N) {
  __shared__ float tile[32][33];
  int n0 = blockIdx.x * 32, k0 = blockIdx.y * 32;
  int tx = threadIdx.x & 31, ty = threadIdx.x >> 5;  // ty 0..7
#pragma unroll
  for (int j = 0; j < 4; ++j) {
    int k = ty + j * 8;
    tile[k][tx] = W[(size_t)(k0 + k) * N + n0 + tx];
  }
  __syncthreads();
#pragma unroll
  for (int j = 0; j < 4; ++j) {
    int n = ty + j * 8;
    Wt[(size_t)(n0 + n) * K + k0 + tx] = f2bf(tile[tx][n]);
  }
}

// ---------------------------------------------------------------- GEMM 128x128
// m97-structure: linear LDS, global_load_lds w=16, no swizzle. T1 XCD-aware
// block remap (bijective: nwg % 8 == 0 for both launches).
// C[M,N] = A[M,K] * Bt[N,K]^T + bias ; A,Bt bf16 ; OUTF32 ? f32 : bf16 out
template <int OUTF32>
__global__ __launch_bounds__(256) void gemm_kernel(
    const unsigned short* __restrict__ A, const unsigned short* __restrict__ Bt,
    const float* __restrict__ bias, void* __restrict__ Cout, int M, int N, int K) {
  __shared__ char lds[32768];
  char* Al = lds;
  char* Bl = lds + 16384;
  // T1: XCD-aware swizzle so each XCD owns a contiguous tile chunk
  int lid = blockIdx.y * gridDim.x + blockIdx.x;
  int chunk = (gridDim.x * gridDim.y) >> 3;
  int swz = (lid & 7) * chunk + (lid >> 3);
  const int n0 = (swz % gridDim.x) * 128, m0 = (swz / gridDim.x) * 128;
  const int w = threadIdx.x >> 6, lane = threadIdx.x & 63;
  const int l15 = lane & 15, g = lane >> 4;
  const int wr = w >> 1, wc = w & 1;
  const int srow = (lane >> 3);       // 0..7 within chunk
  const int u = lane & 7;             // d-octet 0..7
  f32x4 acc[4][4] = {};

  for (int kt = 0; kt < K; kt += 64) {
    __syncthreads();
#pragma unroll
    for (int i = 0; i < 4; ++i) {
      int c = w * 4 + i;              // chunk 0..15, 8 rows each
      int row = c * 8 + srow;         // 0..127
      const unsigned short* srcA = A + (size_t)(m0 + row) * K + kt + u * 8;
      GLOAD_LDS16(srcA, Al + c * 1024);
      const unsigned short* srcB = Bt + (size_t)(n0 + row) * K + kt + u * 8;
      GLOAD_LDS16(srcB, Bl + c * 1024);
    }
    __syncthreads();
#pragma unroll
    for (int kk = 0; kk < 2; ++kk) {
      s16x8 af[4], bfr[4];
#pragma unroll
      for (int mi = 0; mi < 4; ++mi) {
        int row = wr * 64 + mi * 16 + l15;
        af[mi] = *(const s16x8*)(Al + row * 128 + kk * 64 + g * 16);
      }
#pragma unroll
      for (int ni = 0; ni < 4; ++ni) {
        int row = wc * 64 + ni * 16 + l15;
        bfr[ni] = *(const s16x8*)(Bl + row * 128 + kk * 64 + g * 16);
      }
#pragma unroll
      for (int mi = 0; mi < 4; ++mi)
#pragma unroll
        for (int ni = 0; ni < 4; ++ni)
          acc[mi][ni] = MFMA32(af[mi], bfr[ni], acc[mi][ni]);
    }
  }
  // epilogue: D layout col=lane&15, row=(lane>>4)*4+r
#pragma unroll
  for (int ni = 0; ni < 4; ++ni) {
    int col = n0 + wc * 64 + ni * 16 + l15;
    float bv = bias[col];
#pragma unroll
    for (int mi = 0; mi < 4; ++mi) {
      int row = m0 + wr * 64 + mi * 16 + g * 4;
#pragma unroll
      for (int r = 0; r < 4; ++r) {
        float v = acc[mi][ni][r] + bv;
        if (OUTF32)
          ((float*)Cout)[(size_t)(row + r) * N + col] = v;
        else
          ((unsigned short*)Cout)[(size_t)(row + r) * N + col] = f2bf(v);
      }
    }
  }
}

// ---------------------------------------------------------------- attention
// r5/r9-validated structure: QBLK=64, 4 waves, grid (16, B*H) = 1024 blocks =
// 4/CU; block bx processes q-tiles {31-bx, bx} sequentially (33 kv-iters).
// Swapped QK^T: S^T = mfma(A=K, B=Q) -> lane holds keys (g*4+r), q col = l15.
// K: octet-XOR-swizzled ds_write_b128/ds_read_b128.
// V^T: block-padded scatter, stride 76 (38 dw == 6 mod 32; 6*l15 injective
// mod 32 -> PV b64 reads conflict-free; writes bank = 8*vdb+6j+vkey/2 -> all
// 32 banks). Row-sum via ones-MFMA16 (accS). max3 tree reduce. T13 defer-max.
#define VT_STR 76
#define VT_BLK 1232
__global__ __launch_bounds__(256, 4) void attn_kernel(
    const unsigned short* __restrict__ qkv, unsigned short* __restrict__ yatt) {
  __shared__ char lds[8192 + 4 * VT_BLK * 2];  // K 8KB + Vt 9856B; ylds aliases
  const int bx = blockIdx.x;          // 0..15
  const int bh = blockIdx.y;
  const int b = bh >> 4, h = bh & 15;
  const int w = threadIdx.x >> 6;
  const int lane = threadIdx.x & 63;
  const int l15 = lane & 15, g = lane >> 4;

  const size_t rowstride = 3 * D_;  // 3072 elems per token row
  const unsigned short* Qb = qkv + (size_t)b * T_ * rowstride + h * HD_;
  const unsigned short* Kb = Qb + D_;
  const unsigned short* Vb = Qb + 2 * D_;

  char* Klds = lds;
  unsigned short* Vt = (unsigned short*)(lds + 8192);  // [4 blk][16 d][76 key]

  const int krow0 = (w * 2 + 0) * 8 + (lane >> 3);
  const int krow1 = (w * 2 + 1) * 8 + (lane >> 3);
  const int u = lane & 7;
  const int vkey = w * 16 + (lane >> 2);
  const int vdb = lane & 3;
  const float SC = 0.18033688011112042f;  // log2(e)/sqrt(64)
  const s16x4 onesf = {(short)0x3F80, (short)0x3F80, (short)0x3F80, (short)0x3F80};

  const int qtA = 31 - bx;            // first (long) tile; nA = qtA+1 >= 17
  const int nA = qtA + 1;

  // 2-deep prefetch slots (named; rotated by mov -- no runtime indexing)
  s16x8 kc0, kc1, vc0, vc1;  // cur: staged this iter
  s16x8 kn0, kn1, vn0, vn1;  // nxt: staged next iter

  auto ld = [&](int kt, s16x8& a, s16x8& b2, s16x8& c, s16x8& d2) {
    const unsigned short* kb = Kb + (size_t)(kt * 64) * rowstride;
    a = *(const s16x8*)(kb + (size_t)krow0 * rowstride + u * 8);
    b2 = *(const s16x8*)(kb + (size_t)krow1 * rowstride + u * 8);
    const unsigned short* vs = Vb + (size_t)(kt * 64 + vkey) * rowstride + vdb * 16;
    c = *(const s16x8*)(vs);
    d2 = *(const s16x8*)(vs + 8);
  };

  ld(0, kc0, kc1, vc0, vc1);
  ld(1, kn0, kn1, vn0, vn1);
  int f = 0;                  // flat kv-iter counter, 0..32

#pragma unroll 1
  for (int ti = 0; ti < 2; ++ti) {
    const int qt = ti ? bx : qtA;
    // Q fragments with SC pre-folded (B operand: col=l15 -> q row, k=g*8+j -> d)
    s16x8 qf0, qf1;
    {
      const unsigned short* qr = Qb + (size_t)(qt * 64 + w * 16 + l15) * rowstride;
      s16x8 a0 = *(const s16x8*)(qr + g * 8);
      s16x8 a1 = *(const s16x8*)(qr + 32 + g * 8);
#pragma unroll
      for (int j = 0; j < 8; ++j) {
        qf0[j] = (short)f2bf(bf2f((unsigned short)a0[j]) * SC);
        qf1[j] = (short)f2bf(bf2f((unsigned short)a1[j]) * SC);
      }
    }
    float m = -1e30f;
    f32x4 acc[4] = {};  // y^T: acc[db] holds d = db*16 + g*4 + r, q col = l15
    f32x4 accS = {};    // ones-row: accS[r] = running sum of P over keys (all r equal)

#pragma unroll 1
    for (int kt = 0; kt <= qt; ++kt) {
      __syncthreads();
      // K: octet-XOR-swizzled write (reader applies same XOR -> identity)
      *(s16x8*)(Klds + krow0 * 128 + ((u ^ (krow0 & 7)) << 4)) = kc0;
      *(s16x8*)(Klds + krow1 * 128 + ((u ^ (krow1 & 7)) << 4)) = kc1;
      // V^T: block-padded layout, conflict-free writes
#pragma unroll
      for (int j = 0; j < 8; ++j) {
        Vt[vdb * VT_BLK + j * VT_STR + vkey] = (unsigned short)vc0[j];
        Vt[vdb * VT_BLK + (8 + j) * VT_STR + vkey] = (unsigned short)vc1[j];
      }
      __syncthreads();
      // rotate slots and issue the f+2 load (2-deep prefetch)
      kc0 = kn0; kc1 = kn1; vc0 = vn0; vc1 = vn1;
      {
        int f2 = f + 2;
        if (f2 < 33) {
          int kt2 = (f2 < nA) ? f2 : f2 - nA;
          ld(kt2, kn0, kn1, vn0, vn1);
        }
      }

      // QK^T
      float tv[16];
      __builtin_amdgcn_s_setprio(1);
#pragma unroll
      for (int kk = 0; kk < 4; ++kk) {
        int key = kk * 16 + l15;
        const s16x8 kf0 = *(const s16x8*)(Klds + key * 128 + ((g ^ (key & 7)) << 4));
        const s16x8 kf1 = *(const s16x8*)(Klds + key * 128 + (((4 + g) ^ (key & 7)) << 4));
        f32x4 s = {};
        s = MFMA32(kf0, qf0, s);
        s = MFMA32(kf1, qf1, s);
#pragma unroll
        for (int r = 0; r < 4; ++r) tv[kk * 4 + r] = s[r];
      }
      __builtin_amdgcn_s_setprio(0);
      if (kt == qt) {  // diagonal tile: causal mask
        int q = qt * 64 + w * 16 + l15;
#pragma unroll
        for (int kk = 0; kk < 4; ++kk)
#pragma unroll
          for (int r = 0; r < 4; ++r)
            if (kt * 64 + kk * 16 + g * 4 + r > q) tv[kk * 4 + r] = -1e30f;
      }
      // max3-friendly tree reduce + cross-lane
      float a0 = fmaxf(fmaxf(tv[0], tv[1]), tv[2]);
      float a1 = fmaxf(fmaxf(tv[3], tv[4]), tv[5]);
      float a2 = fmaxf(fmaxf(tv[6], tv[7]), tv[8]);
      float a3 = fmaxf(fmaxf(tv[9], tv[10]), tv[11]);
      float a4 = fmaxf(fmaxf(tv[12], tv[13]), tv[14]);
      float b0 = fmaxf(fmaxf(a0, a1), a2);
      float b1 = fmaxf(fmaxf(a3, a4), tv[15]);
      float tm = fmaxf(b0, b1);
      tm = fmaxf(tm, __shfl_xor(tm, 16));
      tm = fmaxf(tm, __shfl_xor(tm, 32));
      if (!__all(tm - m <= 8.0f)) {  // T13 defer-max: P bounded by 2^8
        float mn = fmaxf(m, tm);
        float corr = exp2f(m - mn);
        m = mn;
#pragma unroll
        for (int i = 0; i < 4; ++i) {
          acc[i][0] *= corr; acc[i][1] *= corr;
          acc[i][2] *= corr; acc[i][3] *= corr;
        }
        accS[0] *= corr; accS[1] *= corr; accS[2] *= corr; accS[3] *= corr;
      }
      s16x4 pb[4];
#pragma unroll
      for (int kk = 0; kk < 4; ++kk) {
        float p0 = exp2f(tv[kk * 4 + 0] - m), p1 = exp2f(tv[kk * 4 + 1] - m);
        float p2 = exp2f(tv[kk * 4 + 2] - m), p3 = exp2f(tv[kk * 4 + 3] - m);
        u32x2 pk;  // truncation-pack two hi16s per v_perm
        pk[0] = __builtin_amdgcn_perm(__builtin_bit_cast(unsigned, p1),
                                      __builtin_bit_cast(unsigned, p0), 0x07060302u);
        pk[1] = __builtin_amdgcn_perm(__builtin_bit_cast(unsigned, p3),
                                      __builtin_bit_cast(unsigned, p2), 0x07060302u);
        pb[kk] = __builtin_bit_cast(s16x4, pk);
      }
      // PV: y^T += mfma(A = Vt fragment, B = P^T); row-sum via ones-A MFMA
      __builtin_amdgcn_s_setprio(1);
#pragma unroll
      for (int kk = 0; kk < 4; ++kk) {
#pragma unroll
        for (int db = 0; db < 4; ++db) {
          s16x4 vf = *(const s16x4*)(Vt + db * VT_BLK + l15 * VT_STR + kk * 16 + g * 4);
          acc[db] = MFMA16(vf, pb[kk], acc[db]);
        }
        accS = MFMA16(onesf, pb[kk], accS);
      }
      __builtin_amdgcn_s_setprio(0);
      ++f;
    }

    // epilogue: denom = accS (full row-sum in every lane) + transpose via LDS
    float inv = 1.0f / accS[0];
    __syncthreads();
    unsigned short* ylds = (unsigned short*)lds;  // [64 d][66]
#pragma unroll
    for (int db = 0; db < 4; ++db)
#pragma unroll
      for (int r = 0; r < 4; ++r)
        ylds[(db * 16 + g * 4 + r) * 66 + w * 16 + l15] = f2bf(acc[db][r] * inv);
    __syncthreads();
    int qq = threadIdx.x >> 2;
    int dc = (threadIdx.x & 3) * 16;
    s16x8 o1, o2;
#pragma unroll
    for (int j = 0; j < 8; ++j) {
      o1[j] = (short)ylds[(dc + j) * 66 + qq];
      o2[j] = (short)ylds[(dc + 8 + j) * 66 + qq];
    }
    unsigned short* dst = yatt + (size_t)(b * T_ + qt * 64 + qq) * D_ + h * HD_ + dc;
    *(s16x8*)(dst) = o1;
    *(s16x8*)(dst + 8) = o2;
  }
}

// ---------------------------------------------------------------- launcher
extern "C" void kernel_launch(void* const* d_in, const int* in_sizes, int n_in,
                              void* d_out, int out_size, void* d_ws, size_t ws_size,
                              hipStream_t stream) {
  const float* x     = (const float*)d_in[0];
  const float* Wqkv  = (const float*)d_in[1];
  const float* bqkv  = (const float*)d_in[2];
  const float* Wproj = (const float*)d_in[3];
  const float* bproj = (const float*)d_in[4];
  float* out = (float*)d_out;

  // workspace layout (bf16 buffers), 72 MiB total; yb aliases xb (dead after gemm<0>)
  unsigned short* xb   = (unsigned short*)d_ws;              // [8192][1024]
  unsigned short* Wqb  = xb + (size_t)8192 * 1024;           // [3072][1024] (W_qkv^T)
  unsigned short* Wpb  = Wqb + (size_t)3072 * 1024;          // [1024][1024] (W_proj^T)
  unsigned short* qkvb = Wpb + (size_t)1024 * 1024;          // [8192][3072]
  unsigned short* yb   = xb;                                 // alias: x dead after gemm<0>

  convert_x_kernel<<<dim3(4096), dim3(256), 0, stream>>>(x, xb, 8192 * 1024 / 8);
  transpose_w_kernel<<<dim3(96, 32), dim3(256), 0, stream>>>(Wqkv, Wqb, 1024, 3072);
  transpose_w_kernel<<<dim3(32, 32), dim3(256), 0, stream>>>(Wproj, Wpb, 1024, 1024);
  gemm_kernel<0><<<dim3(24, 64), dim3(256), 0, stream>>>(xb, Wqb, bqkv, qkvb, 8192, 3072, 1024);
  attn_kernel<<<dim3(16, 64), dim3(256), 0, stream>>>(qkvb, yb);
  gemm_kernel<1><<<dim3(8, 64), dim3(256), 0, stream>>>(yb, Wpb, bproj, out, 8192, 1024, 1024);
}

// Round 11
// 203.730 us; speedup vs baseline: 1.9330x; 1.0179x over previous
//
#include <hip/hip_runtime.h>
#include <hip/hip_bf16.h>

// Problem: B=4, T=2048, D=1024, H=16, HD=64
#define B_  4
#define T_  2048
#define D_  1024
#define H_  16
#define HD_ 64

typedef short s16x8 __attribute__((ext_vector_type(8)));
typedef short s16x4 __attribute__((ext_vector_type(4)));
typedef float f32x4 __attribute__((ext_vector_type(4)));
typedef unsigned int u32x2 __attribute__((ext_vector_type(2)));

#define MFMA32(a, b, c) __builtin_amdgcn_mfma_f32_16x16x32_bf16(a, b, c, 0, 0, 0)
#define MFMA16(a, b, c) __builtin_amdgcn_mfma_f32_16x16x16bf16_1k(a, b, c, 0, 0, 0)

__device__ __forceinline__ unsigned short f2bf(float f) {
  unsigned u = __builtin_bit_cast(unsigned, f);
  u += 0x7fffu + ((u >> 16) & 1u);   // RNE
  return (unsigned short)(u >> 16);
}

__device__ __forceinline__ float bf2f(unsigned short h) {
  return __builtin_bit_cast(float, (unsigned)h << 16);
}

#define GLOAD_LDS16(src, dst)                                            \
  __builtin_amdgcn_global_load_lds(                                      \
      (__attribute__((address_space(1))) void*)(void*)(src),             \
      (__attribute__((address_space(3))) void*)(dst), 16, 0, 0)

// ---------------------------------------------------------------- convert x
__global__ __launch_bounds__(256) void convert_x_kernel(
    const float* __restrict__ in, unsigned short* __restrict__ out, int n8) {
  int i = blockIdx.x * 256 + threadIdx.x;
  if (i >= n8) return;
  const float4* p = ((const float4*)in) + (size_t)i * 2;
  float4 a = p[0], b = p[1];
  s16x8 o;
  o[0] = (short)f2bf(a.x); o[1] = (short)f2bf(a.y);
  o[2] = (short)f2bf(a.z); o[3] = (short)f2bf(a.w);
  o[4] = (short)f2bf(b.x); o[5] = (short)f2bf(b.y);
  o[6] = (short)f2bf(b.z); o[7] = (short)f2bf(b.w);
  *(((s16x8*)out) + i) = o;
}

// ------------------------------------------------- transpose W [K][N] -> bf16 [N][K]
__global__ __launch_bounds__(256) void transpose_w_kernel(
    const float* __restrict__ W, unsigned short* __restrict__ Wt, int K, int N) {
  __shared__ float tile[32][33];
  int n0 = blockIdx.x * 32, k0 = blockIdx.y * 32;
  int tx = threadIdx.x & 31, ty = threadIdx.x >> 5;  // ty 0..7
#pragma unroll
  for (int j = 0; j < 4; ++j) {
    int k = ty + j * 8;
    tile[k][tx] = W[(size_t)(k0 + k) * N + n0 + tx];
  }
  __syncthreads();
#pragma unroll
  for (int j = 0; j < 4; ++j) {
    int n = ty + j * 8;
    Wt[(size_t)(n0 + n) * K + k0 + tx] = f2bf(tile[tx][n]);
  }
}

// ---------------------------------------------------------------- GEMM 128x128
// m97-structure: linear LDS, global_load_lds w=16, no swizzle, direct block
// mapping (r10's XCD remap REGRESSED -25us: B stays L2-hot under natural
// round-robin dispatch at this shape; remap forced B streaming).
// C[M,N] = A[M,K] * Bt[N,K]^T + bias ; A,Bt bf16 ; OUTF32 ? f32 : bf16 out
template <int OUTF32>
__global__ __launch_bounds__(256) void gemm_kernel(
    const unsigned short* __restrict__ A, const unsigned short* __restrict__ Bt,
    const float* __restrict__ bias, void* __restrict__ Cout, int M, int N, int K) {
  __shared__ char lds[32768];
  char* Al = lds;
  char* Bl = lds + 16384;
  const int n0 = blockIdx.x * 128, m0 = blockIdx.y * 128;
  const int w = threadIdx.x >> 6, lane = threadIdx.x & 63;
  const int l15 = lane & 15, g = lane >> 4;
  const int wr = w >> 1, wc = w & 1;
  const int srow = (lane >> 3);       // 0..7 within chunk
  const int u = lane & 7;             // d-octet 0..7
  f32x4 acc[4][4] = {};

  for (int kt = 0; kt < K; kt += 64) {
    __syncthreads();
#pragma unroll
    for (int i = 0; i < 4; ++i) {
      int c = w * 4 + i;              // chunk 0..15, 8 rows each
      int row = c * 8 + srow;         // 0..127
      const unsigned short* srcA = A + (size_t)(m0 + row) * K + kt + u * 8;
      GLOAD_LDS16(srcA, Al + c * 1024);
      const unsigned short* srcB = Bt + (size_t)(n0 + row) * K + kt + u * 8;
      GLOAD_LDS16(srcB, Bl + c * 1024);
    }
    __syncthreads();
#pragma unroll
    for (int kk = 0; kk < 2; ++kk) {
      s16x8 af[4], bfr[4];
#pragma unroll
      for (int mi = 0; mi < 4; ++mi) {
        int row = wr * 64 + mi * 16 + l15;
        af[mi] = *(const s16x8*)(Al + row * 128 + kk * 64 + g * 16);
      }
#pragma unroll
      for (int ni = 0; ni < 4; ++ni) {
        int row = wc * 64 + ni * 16 + l15;
        bfr[ni] = *(const s16x8*)(Bl + row * 128 + kk * 64 + g * 16);
      }
#pragma unroll
      for (int mi = 0; mi < 4; ++mi)
#pragma unroll
        for (int ni = 0; ni < 4; ++ni)
          acc[mi][ni] = MFMA32(af[mi], bfr[ni], acc[mi][ni]);
    }
  }
  // epilogue: D layout col=lane&15, row=(lane>>4)*4+r
#pragma unroll
  for (int ni = 0; ni < 4; ++ni) {
    int col = n0 + wc * 64 + ni * 16 + l15;
    float bv = bias[col];
#pragma unroll
    for (int mi = 0; mi < 4; ++mi) {
      int row = m0 + wr * 64 + mi * 16 + g * 4;
#pragma unroll
      for (int r = 0; r < 4; ++r) {
        float v = acc[mi][ni][r] + bv;
        if (OUTF32)
          ((float*)Cout)[(size_t)(row + r) * N + col] = v;
        else
          ((unsigned short*)Cout)[(size_t)(row + r) * N + col] = f2bf(v);
      }
    }
  }
}

// ---------------------------------------------------------------- attention
// r10-validated: QBLK=64, 4 waves, grid (16, B*H) = 1024 blocks = 4/CU;
// block bx processes q-tiles {31-bx, bx} sequentially (33 kv-iters).
// Swapped QK^T: S^T = mfma(A=K, B=Q) -> lane holds keys (g*4+r), q col = l15.
// K: octet-XOR-swizzled ds_write_b128/ds_read_b128.
// V^T: block-padded scatter, stride 76 (6*l15 injective mod 32 -> PV b64
// reads conflict-free). Row-sum via ones-MFMA16. max3 tree. T13 defer-max.
#define VT_STR 76
#define VT_BLK 1232
__global__ __launch_bounds__(256, 4) void attn_kernel(
    const unsigned short* __restrict__ qkv, unsigned short* __restrict__ yatt) {
  __shared__ char lds[8192 + 4 * VT_BLK * 2];  // K 8KB + Vt 9856B; ylds aliases
  const int bx = blockIdx.x;          // 0..15
  const int bh = blockIdx.y;
  const int b = bh >> 4, h = bh & 15;
  const int w = threadIdx.x >> 6;
  const int lane = threadIdx.x & 63;
  const int l15 = lane & 15, g = lane >> 4;

  const size_t rowstride = 3 * D_;  // 3072 elems per token row
  const unsigned short* Qb = qkv + (size_t)b * T_ * rowstride + h * HD_;
  const unsigned short* Kb = Qb + D_;
  const unsigned short* Vb = Qb + 2 * D_;

  char* Klds = lds;
  unsigned short* Vt = (unsigned short*)(lds + 8192);  // [4 blk][16 d][76 key]

  const int krow0 = (w * 2 + 0) * 8 + (lane >> 3);
  const int krow1 = (w * 2 + 1) * 8 + (lane >> 3);
  const int u = lane & 7;
  const int vkey = w * 16 + (lane >> 2);
  const int vdb = lane & 3;
  const float SC = 0.18033688011112042f;  // log2(e)/sqrt(64)
  const s16x4 onesf = {(short)0x3F80, (short)0x3F80, (short)0x3F80, (short)0x3F80};

  const int qtA = 31 - bx;            // first (long) tile; nA = qtA+1 >= 17
  const int nA = qtA + 1;

  // 2-deep prefetch slots (named; rotated by mov -- no runtime indexing)
  s16x8 kc0, kc1, vc0, vc1;  // cur: staged this iter
  s16x8 kn0, kn1, vn0, vn1;  // nxt: staged next iter

  auto ld = [&](int kt, s16x8& a, s16x8& b2, s16x8& c, s16x8& d2) {
    const unsigned short* kb = Kb + (size_t)(kt * 64) * rowstride;
    a = *(const s16x8*)(kb + (size_t)krow0 * rowstride + u * 8);
    b2 = *(const s16x8*)(kb + (size_t)krow1 * rowstride + u * 8);
    const unsigned short* vs = Vb + (size_t)(kt * 64 + vkey) * rowstride + vdb * 16;
    c = *(const s16x8*)(vs);
    d2 = *(const s16x8*)(vs + 8);
  };

  ld(0, kc0, kc1, vc0, vc1);
  ld(1, kn0, kn1, vn0, vn1);
  int f = 0;                  // flat kv-iter counter, 0..32

#pragma unroll 1
  for (int ti = 0; ti < 2; ++ti) {
    const int qt = ti ? bx : qtA;
    // Q fragments with SC pre-folded (B operand: col=l15 -> q row, k=g*8+j -> d)
    s16x8 qf0, qf1;
    {
      const unsigned short* qr = Qb + (size_t)(qt * 64 + w * 16 + l15) * rowstride;
      s16x8 a0 = *(const s16x8*)(qr + g * 8);
      s16x8 a1 = *(const s16x8*)(qr + 32 + g * 8);
#pragma unroll
      for (int j = 0; j < 8; ++j) {
        qf0[j] = (short)f2bf(bf2f((unsigned short)a0[j]) * SC);
        qf1[j] = (short)f2bf(bf2f((unsigned short)a1[j]) * SC);
      }
    }
    float m = -1e30f;
    f32x4 acc[4] = {};  // y^T: acc[db] holds d = db*16 + g*4 + r, q col = l15
    f32x4 accS = {};    // ones-row: accS[r] = running sum of P over keys

#pragma unroll 1
    for (int kt = 0; kt <= qt; ++kt) {
      __syncthreads();
      // K: octet-XOR-swizzled write (reader applies same XOR -> identity)
      *(s16x8*)(Klds + krow0 * 128 + ((u ^ (krow0 & 7)) << 4)) = kc0;
      *(s16x8*)(Klds + krow1 * 128 + ((u ^ (krow1 & 7)) << 4)) = kc1;
      // V^T: block-padded layout, conflict-free writes
#pragma unroll
      for (int j = 0; j < 8; ++j) {
        Vt[vdb * VT_BLK + j * VT_STR + vkey] = (unsigned short)vc0[j];
        Vt[vdb * VT_BLK + (8 + j) * VT_STR + vkey] = (unsigned short)vc1[j];
      }
      __syncthreads();
      // rotate slots and issue the f+2 load (2-deep prefetch)
      kc0 = kn0; kc1 = kn1; vc0 = vn0; vc1 = vn1;
      {
        int f2 = f + 2;
        if (f2 < 33) {
          int kt2 = (f2 < nA) ? f2 : f2 - nA;
          ld(kt2, kn0, kn1, vn0, vn1);
        }
      }

      // QK^T
      float tv[16];
      __builtin_amdgcn_s_setprio(1);
#pragma unroll
      for (int kk = 0; kk < 4; ++kk) {
        int key = kk * 16 + l15;
        const s16x8 kf0 = *(const s16x8*)(Klds + key * 128 + ((g ^ (key & 7)) << 4));
        const s16x8 kf1 = *(const s16x8*)(Klds + key * 128 + (((4 + g) ^ (key & 7)) << 4));
        f32x4 s = {};
        s = MFMA32(kf0, qf0, s);
        s = MFMA32(kf1, qf1, s);
#pragma unroll
        for (int r = 0; r < 4; ++r) tv[kk * 4 + r] = s[r];
      }
      __builtin_amdgcn_s_setprio(0);
      if (kt == qt) {  // diagonal tile: causal mask
        int q = qt * 64 + w * 16 + l15;
#pragma unroll
        for (int kk = 0; kk < 4; ++kk)
#pragma unroll
          for (int r = 0; r < 4; ++r)
            if (kt * 64 + kk * 16 + g * 4 + r > q) tv[kk * 4 + r] = -1e30f;
      }
      // max3-friendly tree reduce + cross-lane
      float a0 = fmaxf(fmaxf(tv[0], tv[1]), tv[2]);
      float a1 = fmaxf(fmaxf(tv[3], tv[4]), tv[5]);
      float a2 = fmaxf(fmaxf(tv[6], tv[7]), tv[8]);
      float a3 = fmaxf(fmaxf(tv[9], tv[10]), tv[11]);
      float a4 = fmaxf(fmaxf(tv[12], tv[13]), tv[14]);
      float b0 = fmaxf(fmaxf(a0, a1), a2);
      float b1 = fmaxf(fmaxf(a3, a4), tv[15]);
      float tm = fmaxf(b0, b1);
      tm = fmaxf(tm, __shfl_xor(tm, 16));
      tm = fmaxf(tm, __shfl_xor(tm, 32));
      if (!__all(tm - m <= 8.0f)) {  // T13 defer-max: P bounded by 2^8
        float mn = fmaxf(m, tm);
        float corr = exp2f(m - mn);
        m = mn;
#pragma unroll
        for (int i = 0; i < 4; ++i) {
          acc[i][0] *= corr; acc[i][1] *= corr;
          acc[i][2] *= corr; acc[i][3] *= corr;
        }
        accS[0] *= corr; accS[1] *= corr; accS[2] *= corr; accS[3] *= corr;
      }
      s16x4 pb[4];
#pragma unroll
      for (int kk = 0; kk < 4; ++kk) {
        float p0 = exp2f(tv[kk * 4 + 0] - m), p1 = exp2f(tv[kk * 4 + 1] - m);
        float p2 = exp2f(tv[kk * 4 + 2] - m), p3 = exp2f(tv[kk * 4 + 3] - m);
        u32x2 pk;  // truncation-pack two hi16s per v_perm
        pk[0] = __builtin_amdgcn_perm(__builtin_bit_cast(unsigned, p1),
                                      __builtin_bit_cast(unsigned, p0), 0x07060302u);
        pk[1] = __builtin_amdgcn_perm(__builtin_bit_cast(unsigned, p3),
                                      __builtin_bit_cast(unsigned, p2), 0x07060302u);
        pb[kk] = __builtin_bit_cast(s16x4, pk);
      }
      // PV: y^T += mfma(A = Vt fragment, B = P^T); row-sum via ones-A MFMA
      __builtin_amdgcn_s_setprio(1);
#pragma unroll
      for (int kk = 0; kk < 4; ++kk) {
#pragma unroll
        for (int db = 0; db < 4; ++db) {
          s16x4 vf = *(const s16x4*)(Vt + db * VT_BLK + l15 * VT_STR + kk * 16 + g * 4);
          acc[db] = MFMA16(vf, pb[kk], acc[db]);
        }
        accS = MFMA16(onesf, pb[kk], accS);
      }
      __builtin_amdgcn_s_setprio(0);
      ++f;
    }

    // epilogue: denom = accS (full row-sum in every lane) + transpose via LDS
    float inv = 1.0f / accS[0];
    __syncthreads();
    unsigned short* ylds = (unsigned short*)lds;  // [64 d][66]
#pragma unroll
    for (int db = 0; db < 4; ++db)
#pragma unroll
      for (int r = 0; r < 4; ++r)
        ylds[(db * 16 + g * 4 + r) * 66 + w * 16 + l15] = f2bf(acc[db][r] * inv);
    __syncthreads();
    int qq = threadIdx.x >> 2;
    int dc = (threadIdx.x & 3) * 16;
    s16x8 o1, o2;
#pragma unroll
    for (int j = 0; j < 8; ++j) {
      o1[j] = (short)ylds[(dc + j) * 66 + qq];
      o2[j] = (short)ylds[(dc + 8 + j) * 66 + qq];
    }
    unsigned short* dst = yatt + (size_t)(b * T_ + qt * 64 + qq) * D_ + h * HD_ + dc;
    *(s16x8*)(dst) = o1;
    *(s16x8*)(dst + 8) = o2;
  }
}

// ---------------------------------------------------------------- launcher
extern "C" void kernel_launch(void* const* d_in, const int* in_sizes, int n_in,
                              void* d_out, int out_size, void* d_ws, size_t ws_size,
                              hipStream_t stream) {
  const float* x     = (const float*)d_in[0];
  const float* Wqkv  = (const float*)d_in[1];
  const float* bqkv  = (const float*)d_in[2];
  const float* Wproj = (const float*)d_in[3];
  const float* bproj = (const float*)d_in[4];
  float* out = (float*)d_out;

  // workspace layout (bf16 buffers), 72 MiB total; yb aliases xb (dead after gemm<0>)
  unsigned short* xb   = (unsigned short*)d_ws;              // [8192][1024]
  unsigned short* Wqb  = xb + (size_t)8192 * 1024;           // [3072][1024] (W_qkv^T)
  unsigned short* Wpb  = Wqb + (size_t)3072 * 1024;          // [1024][1024] (W_proj^T)
  unsigned short* qkvb = Wpb + (size_t)1024 * 1024;          // [8192][3072]
  unsigned short* yb   = xb;                                 // alias: x dead after gemm<0>

  convert_x_kernel<<<dim3(4096), dim3(256), 0, stream>>>(x, xb, 8192 * 1024 / 8);
  transpose_w_kernel<<<dim3(96, 32), dim3(256), 0, stream>>>(Wqkv, Wqb, 1024, 3072);
  transpose_w_kernel<<<dim3(32, 32), dim3(256), 0, stream>>>(Wproj, Wpb, 1024, 1024);
  gemm_kernel<0><<<dim3(24, 64), dim3(256), 0, stream>>>(xb, Wqb, bqkv, qkvb, 8192, 3072, 1024);
  attn_kernel<<<dim3(16, 64), dim3(256), 0, stream>>>(qkvb, yb);
  gemm_kernel<1><<<dim3(8, 64), dim3(256), 0, stream>>>(yb, Wpb, bproj, out, 8192, 1024, 1024);
}

// Round 12
// 194.183 us; speedup vs baseline: 2.0280x; 1.0492x over previous
//
#include <hip/hip_runtime.h>
#include <hip/hip_bf16.h>

// Problem: B=4, T=2048, D=1024, H=16, HD=64
#define B_  4
#define T_  2048
#define D_  1024
#define H_  16
#define HD_ 64

typedef short s16x8 __attribute__((ext_vector_type(8)));
typedef short s16x4 __attribute__((ext_vector_type(4)));
typedef float f32x4 __attribute__((ext_vector_type(4)));
typedef unsigned int u32x2 __attribute__((ext_vector_type(2)));

#define MFMA32(a, b, c) __builtin_amdgcn_mfma_f32_16x16x32_bf16(a, b, c, 0, 0, 0)
#define MFMA16(a, b, c) __builtin_amdgcn_mfma_f32_16x16x16bf16_1k(a, b, c, 0, 0, 0)

__device__ __forceinline__ unsigned short f2bf(float f) {
  unsigned u = __builtin_bit_cast(unsigned, f);
  u += 0x7fffu + ((u >> 16) & 1u);   // RNE
  return (unsigned short)(u >> 16);
}

__device__ __forceinline__ float bf2f(unsigned short h) {
  return __builtin_bit_cast(float, (unsigned)h << 16);
}

#define GLOAD_LDS16(src, dst)                                            \
  __builtin_amdgcn_global_load_lds(                                      \
      (__attribute__((address_space(1))) void*)(void*)(src),             \
      (__attribute__((address_space(3))) void*)(dst), 16, 0, 0)

// ---------------------------------------------------------------- convert x
__global__ __launch_bounds__(256) void convert_x_kernel(
    const float* __restrict__ in, unsigned short* __restrict__ out, int n8) {
  int i = blockIdx.x * 256 + threadIdx.x;
  if (i >= n8) return;
  const float4* p = ((const float4*)in) + (size_t)i * 2;
  float4 a = p[0], b = p[1];
  s16x8 o;
  o[0] = (short)f2bf(a.x); o[1] = (short)f2bf(a.y);
  o[2] = (short)f2bf(a.z); o[3] = (short)f2bf(a.w);
  o[4] = (short)f2bf(b.x); o[5] = (short)f2bf(b.y);
  o[6] = (short)f2bf(b.z); o[7] = (short)f2bf(b.w);
  *(((s16x8*)out) + i) = o;
}

// ------------------------------------------------- transpose W [K][N] -> bf16 [N][K]
__global__ __launch_bounds__(256) void transpose_w_kernel(
    const float* __restrict__ W, unsigned short* __restrict__ Wt, int K, int N) {
  __shared__ float tile[32][33];
  int n0 = blockIdx.x * 32, k0 = blockIdx.y * 32;
  int tx = threadIdx.x & 31, ty = threadIdx.x >> 5;  // ty 0..7
#pragma unroll
  for (int j = 0; j < 4; ++j) {
    int k = ty + j * 8;
    tile[k][tx] = W[(size_t)(k0 + k) * N + n0 + tx];
  }
  __syncthreads();
#pragma unroll
  for (int j = 0; j < 4; ++j) {
    int n = ty + j * 8;
    Wt[(size_t)(n0 + n) * K + k0 + tx] = f2bf(tile[tx][n]);
  }
}

// ---------------------------------------------------------------- GEMM 128x128
// m97-structure + BOTH-SIDES octet-XOR swizzle (rule #21): linear LDS dest,
// inverse-swizzled global source, swizzled ds_read. Staging puts global octet
// ug at LDS octet ug^(row&7); read fetches octet (kk*4+g)^(row&7) -> banks
// 4*(g^(l15&7)) span all 32, 2-way only (was 16-way: row*128B = bank-aligned).
// C[M,N] = A[M,K] * Bt[N,K]^T + bias ; A,Bt bf16 ; OUTF32 ? f32 : bf16 out
template <int OUTF32>
__global__ __launch_bounds__(256) void gemm_kernel(
    const unsigned short* __restrict__ A, const unsigned short* __restrict__ Bt,
    const float* __restrict__ bias, void* __restrict__ Cout, int M, int N, int K) {
  __shared__ char lds[32768];
  char* Al = lds;
  char* Bl = lds + 16384;
  const int n0 = blockIdx.x * 128, m0 = blockIdx.y * 128;
  const int w = threadIdx.x >> 6, lane = threadIdx.x & 63;
  const int l15 = lane & 15, g = lane >> 4;
  const int wr = w >> 1, wc = w & 1;
  const int srow = (lane >> 3);       // 0..7 within chunk (= row & 7)
  const int u = lane & 7;             // d-octet 0..7
  const int soct = (u ^ srow) << 3;   // inverse-swizzled source octet (elems)
  const int rx = l15 & 7;             // read-side row&7
  f32x4 acc[4][4] = {};

  for (int kt = 0; kt < K; kt += 64) {
    __syncthreads();
#pragma unroll
    for (int i = 0; i < 4; ++i) {
      int c = w * 4 + i;              // chunk 0..15, 8 rows each
      int row = c * 8 + srow;         // 0..127 (row & 7 == srow)
      const unsigned short* srcA = A + (size_t)(m0 + row) * K + kt + soct;
      GLOAD_LDS16(srcA, Al + c * 1024);
      const unsigned short* srcB = Bt + (size_t)(n0 + row) * K + kt + soct;
      GLOAD_LDS16(srcB, Bl + c * 1024);
    }
    __syncthreads();
#pragma unroll
    for (int kk = 0; kk < 2; ++kk) {
      const int roct = ((kk * 4 + g) ^ rx) << 4;  // swizzled read octet (bytes)
      s16x8 af[4], bfr[4];
#pragma unroll
      for (int mi = 0; mi < 4; ++mi) {
        int row = wr * 64 + mi * 16 + l15;
        af[mi] = *(const s16x8*)(Al + row * 128 + roct);
      }
#pragma unroll
      for (int ni = 0; ni < 4; ++ni) {
        int row = wc * 64 + ni * 16 + l15;
        bfr[ni] = *(const s16x8*)(Bl + row * 128 + roct);
      }
#pragma unroll
      for (int mi = 0; mi < 4; ++mi)
#pragma unroll
        for (int ni = 0; ni < 4; ++ni)
          acc[mi][ni] = MFMA32(af[mi], bfr[ni], acc[mi][ni]);
    }
  }
  // epilogue: D layout col=lane&15, row=(lane>>4)*4+r
#pragma unroll
  for (int ni = 0; ni < 4; ++ni) {
    int col = n0 + wc * 64 + ni * 16 + l15;
    float bv = bias[col];
#pragma unroll
    for (int mi = 0; mi < 4; ++mi) {
      int row = m0 + wr * 64 + mi * 16 + g * 4;
#pragma unroll
      for (int r = 0; r < 4; ++r) {
        float v = acc[mi][ni][r] + bv;
        if (OUTF32)
          ((float*)Cout)[(size_t)(row + r) * N + col] = v;
        else
          ((unsigned short*)Cout)[(size_t)(row + r) * N + col] = f2bf(v);
      }
    }
  }
}

// ---------------------------------------------------------------- attention
// r10/r11-validated: QBLK=64, 4 waves, grid (16, B*H) = 1024 blocks = 4/CU;
// block bx processes q-tiles {31-bx, bx} sequentially (33 kv-iters).
// Swapped QK^T: S^T = mfma(A=K, B=Q) -> lane holds keys (g*4+r), q col = l15.
// K: octet-XOR-swizzled ds_write_b128/ds_read_b128.
// V^T: block-padded scatter, stride 76 (6*l15 injective mod 32 -> PV b64
// reads conflict-free). Row-sum via ones-MFMA16. max3 tree. T13 defer-max.
#define VT_STR 76
#define VT_BLK 1232
__global__ __launch_bounds__(256, 4) void attn_kernel(
    const unsigned short* __restrict__ qkv, unsigned short* __restrict__ yatt) {
  __shared__ char lds[8192 + 4 * VT_BLK * 2];  // K 8KB + Vt 9856B; ylds aliases
  const int bx = blockIdx.x;          // 0..15
  const int bh = blockIdx.y;
  const int b = bh >> 4, h = bh & 15;
  const int w = threadIdx.x >> 6;
  const int lane = threadIdx.x & 63;
  const int l15 = lane & 15, g = lane >> 4;

  const size_t rowstride = 3 * D_;  // 3072 elems per token row
  const unsigned short* Qb = qkv + (size_t)b * T_ * rowstride + h * HD_;
  const unsigned short* Kb = Qb + D_;
  const unsigned short* Vb = Qb + 2 * D_;

  char* Klds = lds;
  unsigned short* Vt = (unsigned short*)(lds + 8192);  // [4 blk][16 d][76 key]

  const int krow0 = (w * 2 + 0) * 8 + (lane >> 3);
  const int krow1 = (w * 2 + 1) * 8 + (lane >> 3);
  const int u = lane & 7;
  const int vkey = w * 16 + (lane >> 2);
  const int vdb = lane & 3;
  const float SC = 0.18033688011112042f;  // log2(e)/sqrt(64)
  const s16x4 onesf = {(short)0x3F80, (short)0x3F80, (short)0x3F80, (short)0x3F80};

  const int qtA = 31 - bx;            // first (long) tile; nA = qtA+1 >= 17
  const int nA = qtA + 1;

  // 2-deep prefetch slots (named; rotated by mov -- no runtime indexing)
  s16x8 kc0, kc1, vc0, vc1;  // cur: staged this iter
  s16x8 kn0, kn1, vn0, vn1;  // nxt: staged next iter

  auto ld = [&](int kt, s16x8& a, s16x8& b2, s16x8& c, s16x8& d2) {
    const unsigned short* kb = Kb + (size_t)(kt * 64) * rowstride;
    a = *(const s16x8*)(kb + (size_t)krow0 * rowstride + u * 8);
    b2 = *(const s16x8*)(kb + (size_t)krow1 * rowstride + u * 8);
    const unsigned short* vs = Vb + (size_t)(kt * 64 + vkey) * rowstride + vdb * 16;
    c = *(const s16x8*)(vs);
    d2 = *(const s16x8*)(vs + 8);
  };

  ld(0, kc0, kc1, vc0, vc1);
  ld(1, kn0, kn1, vn0, vn1);
  int f = 0;                  // flat kv-iter counter, 0..32

#pragma unroll 1
  for (int ti = 0; ti < 2; ++ti) {
    const int qt = ti ? bx : qtA;
    // Q fragments with SC pre-folded (B operand: col=l15 -> q row, k=g*8+j -> d)
    s16x8 qf0, qf1;
    {
      const unsigned short* qr = Qb + (size_t)(qt * 64 + w * 16 + l15) * rowstride;
      s16x8 a0 = *(const s16x8*)(qr + g * 8);
      s16x8 a1 = *(const s16x8*)(qr + 32 + g * 8);
#pragma unroll
      for (int j = 0; j < 8; ++j) {
        qf0[j] = (short)f2bf(bf2f((unsigned short)a0[j]) * SC);
        qf1[j] = (short)f2bf(bf2f((unsigned short)a1[j]) * SC);
      }
    }
    float m = -1e30f;
    f32x4 acc[4] = {};  // y^T: acc[db] holds d = db*16 + g*4 + r, q col = l15
    f32x4 accS = {};    // ones-row: accS[r] = running sum of P over keys

#pragma unroll 1
    for (int kt = 0; kt <= qt; ++kt) {
      __syncthreads();
      // K: octet-XOR-swizzled write (reader applies same XOR -> identity)
      *(s16x8*)(Klds + krow0 * 128 + ((u ^ (krow0 & 7)) << 4)) = kc0;
      *(s16x8*)(Klds + krow1 * 128 + ((u ^ (krow1 & 7)) << 4)) = kc1;
      // V^T: block-padded layout, conflict-free writes
#pragma unroll
      for (int j = 0; j < 8; ++j) {
        Vt[vdb * VT_BLK + j * VT_STR + vkey] = (unsigned short)vc0[j];
        Vt[vdb * VT_BLK + (8 + j) * VT_STR + vkey] = (unsigned short)vc1[j];
      }
      __syncthreads();
      // rotate slots and issue the f+2 load (2-deep prefetch)
      kc0 = kn0; kc1 = kn1; vc0 = vn0; vc1 = vn1;
      {
        int f2 = f + 2;
        if (f2 < 33) {
          int kt2 = (f2 < nA) ? f2 : f2 - nA;
          ld(kt2, kn0, kn1, vn0, vn1);
        }
      }

      // QK^T
      float tv[16];
      __builtin_amdgcn_s_setprio(1);
#pragma unroll
      for (int kk = 0; kk < 4; ++kk) {
        int key = kk * 16 + l15;
        const s16x8 kf0 = *(const s16x8*)(Klds + key * 128 + ((g ^ (key & 7)) << 4));
        const s16x8 kf1 = *(const s16x8*)(Klds + key * 128 + (((4 + g) ^ (key & 7)) << 4));
        f32x4 s = {};
        s = MFMA32(kf0, qf0, s);
        s = MFMA32(kf1, qf1, s);
#pragma unroll
        for (int r = 0; r < 4; ++r) tv[kk * 4 + r] = s[r];
      }
      __builtin_amdgcn_s_setprio(0);
      if (kt == qt) {  // diagonal tile: causal mask
        int q = qt * 64 + w * 16 + l15;
#pragma unroll
        for (int kk = 0; kk < 4; ++kk)
#pragma unroll
          for (int r = 0; r < 4; ++r)
            if (kt * 64 + kk * 16 + g * 4 + r > q) tv[kk * 4 + r] = -1e30f;
      }
      // max3-friendly tree reduce + cross-lane
      float a0 = fmaxf(fmaxf(tv[0], tv[1]), tv[2]);
      float a1 = fmaxf(fmaxf(tv[3], tv[4]), tv[5]);
      float a2 = fmaxf(fmaxf(tv[6], tv[7]), tv[8]);
      float a3 = fmaxf(fmaxf(tv[9], tv[10]), tv[11]);
      float a4 = fmaxf(fmaxf(tv[12], tv[13]), tv[14]);
      float b0 = fmaxf(fmaxf(a0, a1), a2);
      float b1 = fmaxf(fmaxf(a3, a4), tv[15]);
      float tm = fmaxf(b0, b1);
      tm = fmaxf(tm, __shfl_xor(tm, 16));
      tm = fmaxf(tm, __shfl_xor(tm, 32));
      if (!__all(tm - m <= 8.0f)) {  // T13 defer-max: P bounded by 2^8
        float mn = fmaxf(m, tm);
        float corr = exp2f(m - mn);
        m = mn;
#pragma unroll
        for (int i = 0; i < 4; ++i) {
          acc[i][0] *= corr; acc[i][1] *= corr;
          acc[i][2] *= corr; acc[i][3] *= corr;
        }
        accS[0] *= corr; accS[1] *= corr; accS[2] *= corr; accS[3] *= corr;
      }
      s16x4 pb[4];
#pragma unroll
      for (int kk = 0; kk < 4; ++kk) {
        float p0 = exp2f(tv[kk * 4 + 0] - m), p1 = exp2f(tv[kk * 4 + 1] - m);
        float p2 = exp2f(tv[kk * 4 + 2] - m), p3 = exp2f(tv[kk * 4 + 3] - m);
        u32x2 pk;  // truncation-pack two hi16s per v_perm
        pk[0] = __builtin_amdgcn_perm(__builtin_bit_cast(unsigned, p1),
                                      __builtin_bit_cast(unsigned, p0), 0x07060302u);
        pk[1] = __builtin_amdgcn_perm(__builtin_bit_cast(unsigned, p3),
                                      __builtin_bit_cast(unsigned, p2), 0x07060302u);
        pb[kk] = __builtin_bit_cast(s16x4, pk);
      }
      // PV: y^T += mfma(A = Vt fragment, B = P^T); row-sum via ones-A MFMA
      __builtin_amdgcn_s_setprio(1);
#pragma unroll
      for (int kk = 0; kk < 4; ++kk) {
#pragma unroll
        for (int db = 0; db < 4; ++db) {
          s16x4 vf = *(const s16x4*)(Vt + db * VT_BLK + l15 * VT_STR + kk * 16 + g * 4);
          acc[db] = MFMA16(vf, pb[kk], acc[db]);
        }
        accS = MFMA16(onesf, pb[kk], accS);
      }
      __builtin_amdgcn_s_setprio(0);
      ++f;
    }

    // epilogue: denom = accS (full row-sum in every lane) + transpose via LDS
    float inv = 1.0f / accS[0];
    __syncthreads();
    unsigned short* ylds = (unsigned short*)lds;  // [64 d][66]
#pragma unroll
    for (int db = 0; db < 4; ++db)
#pragma unroll
      for (int r = 0; r < 4; ++r)
        ylds[(db * 16 + g * 4 + r) * 66 + w * 16 + l15] = f2bf(acc[db][r] * inv);
    __syncthreads();
    int qq = threadIdx.x >> 2;
    int dc = (threadIdx.x & 3) * 16;
    s16x8 o1, o2;
#pragma unroll
    for (int j = 0; j < 8; ++j) {
      o1[j] = (short)ylds[(dc + j) * 66 + qq];
      o2[j] = (short)ylds[(dc + 8 + j) * 66 + qq];
    }
    unsigned short* dst = yatt + (size_t)(b * T_ + qt * 64 + qq) * D_ + h * HD_ + dc;
    *(s16x8*)(dst) = o1;
    *(s16x8*)(dst + 8) = o2;
  }
}

// ---------------------------------------------------------------- launcher
extern "C" void kernel_launch(void* const* d_in, const int* in_sizes, int n_in,
                              void* d_out, int out_size, void* d_ws, size_t ws_size,
                              hipStream_t stream) {
  const float* x     = (const float*)d_in[0];
  const float* Wqkv  = (const float*)d_in[1];
  const float* bqkv  = (const float*)d_in[2];
  const float* Wproj = (const float*)d_in[3];
  const float* bproj = (const float*)d_in[4];
  float* out = (float*)d_out;

  // workspace layout (bf16 buffers), 72 MiB total; yb aliases xb (dead after gemm<0>)
  unsigned short* xb   = (unsigned short*)d_ws;              // [8192][1024]
  unsigned short* Wqb  = xb + (size_t)8192 * 1024;           // [3072][1024] (W_qkv^T)
  unsigned short* Wpb  = Wqb + (size_t)3072 * 1024;          // [1024][1024] (W_proj^T)
  unsigned short* qkvb = Wpb + (size_t)1024 * 1024;          // [8192][3072]
  unsigned short* yb   = xb;                                 // alias: x dead after gemm<0>

  convert_x_kernel<<<dim3(4096), dim3(256), 0, stream>>>(x, xb, 8192 * 1024 / 8);
  transpose_w_kernel<<<dim3(96, 32), dim3(256), 0, stream>>>(Wqkv, Wqb, 1024, 3072);
  transpose_w_kernel<<<dim3(32, 32), dim3(256), 0, stream>>>(Wproj, Wpb, 1024, 1024);
  gemm_kernel<0><<<dim3(24, 64), dim3(256), 0, stream>>>(xb, Wqb, bqkv, qkvb, 8192, 3072, 1024);
  attn_kernel<<<dim3(16, 64), dim3(256), 0, stream>>>(qkvb, yb);
  gemm_kernel<1><<<dim3(8, 64), dim3(256), 0, stream>>>(yb, Wpb, bproj, out, 8192, 1024, 1024);
}

// Round 13
// 193.207 us; speedup vs baseline: 2.0383x; 1.0050x over previous
//
#include <hip/hip_runtime.h>
#include <hip/hip_bf16.h>

// Problem: B=4, T=2048, D=1024, H=16, HD=64
#define B_  4
#define T_  2048
#define D_  1024
#define H_  16
#define HD_ 64

typedef short s16x8 __attribute__((ext_vector_type(8)));
typedef short s16x4 __attribute__((ext_vector_type(4)));
typedef float f32x4 __attribute__((ext_vector_type(4)));
typedef unsigned int u32x2 __attribute__((ext_vector_type(2)));

#define MFMA32(a, b, c) __builtin_amdgcn_mfma_f32_16x16x32_bf16(a, b, c, 0, 0, 0)
#define MFMA16(a, b, c) __builtin_amdgcn_mfma_f32_16x16x16bf16_1k(a, b, c, 0, 0, 0)

__device__ __forceinline__ unsigned short f2bf(float f) {
  unsigned u = __builtin_bit_cast(unsigned, f);
  u += 0x7fffu + ((u >> 16) & 1u);   // RNE
  return (unsigned short)(u >> 16);
}

__device__ __forceinline__ float bf2f(unsigned short h) {
  return __builtin_bit_cast(float, (unsigned)h << 16);
}

#define GLOAD_LDS16(src, dst)                                            \
  __builtin_amdgcn_global_load_lds(                                      \
      (__attribute__((address_space(1))) void*)(void*)(src),             \
      (__attribute__((address_space(3))) void*)(dst), 16, 0, 0)

// ---------------------------------------------------------------- convert x
__global__ __launch_bounds__(256) void convert_x_kernel(
    const float* __restrict__ in, unsigned short* __restrict__ out, int n8) {
  int i = blockIdx.x * 256 + threadIdx.x;
  if (i >= n8) return;
  const float4* p = ((const float4*)in) + (size_t)i * 2;
  float4 a = p[0], b = p[1];
  s16x8 o;
  o[0] = (short)f2bf(a.x); o[1] = (short)f2bf(a.y);
  o[2] = (short)f2bf(a.z); o[3] = (short)f2bf(a.w);
  o[4] = (short)f2bf(b.x); o[5] = (short)f2bf(b.y);
  o[6] = (short)f2bf(b.z); o[7] = (short)f2bf(b.w);
  *(((s16x8*)out) + i) = o;
}

// ------------------------------------------------- transpose W [K][N] -> bf16 [N][K]
__global__ __launch_bounds__(256) void transpose_w_kernel(
    const float* __restrict__ W, unsigned short* __restrict__ Wt, int K, int N) {
  __shared__ float tile[32][33];
  int n0 = blockIdx.x * 32, k0 = blockIdx.y * 32;
  int tx = threadIdx.x & 31, ty = threadIdx.x >> 5;  // ty 0..7
#pragma unroll
  for (int j = 0; j < 4; ++j) {
    int k = ty + j * 8;
    tile[k][tx] = W[(size_t)(k0 + k) * N + n0 + tx];
  }
  __syncthreads();
#pragma unroll
  for (int j = 0; j < 4; ++j) {
    int n = ty + j * 8;
    Wt[(size_t)(n0 + n) * K + k0 + tx] = f2bf(tile[tx][n]);
  }
}

// ---------------------------------------------------------------- GEMM 128x128
// m97-structure + BOTH-SIDES octet-XOR swizzle (r12-validated: conflicts
// 1.9e7 -> ~0, 94 -> ~60us). Linear LDS dest, inverse-swizzled global source,
// swizzled ds_read.
template <int OUTF32>
__global__ __launch_bounds__(256) void gemm_kernel(
    const unsigned short* __restrict__ A, const unsigned short* __restrict__ Bt,
    const float* __restrict__ bias, void* __restrict__ Cout, int M, int N, int K) {
  __shared__ char lds[32768];
  char* Al = lds;
  char* Bl = lds + 16384;
  const int n0 = blockIdx.x * 128, m0 = blockIdx.y * 128;
  const int w = threadIdx.x >> 6, lane = threadIdx.x & 63;
  const int l15 = lane & 15, g = lane >> 4;
  const int wr = w >> 1, wc = w & 1;
  const int srow = (lane >> 3);       // 0..7 within chunk (= row & 7)
  const int u = lane & 7;             // d-octet 0..7
  const int soct = (u ^ srow) << 3;   // inverse-swizzled source octet (elems)
  const int rx = l15 & 7;             // read-side row&7
  f32x4 acc[4][4] = {};

  for (int kt = 0; kt < K; kt += 64) {
    __syncthreads();
#pragma unroll
    for (int i = 0; i < 4; ++i) {
      int c = w * 4 + i;              // chunk 0..15, 8 rows each
      int row = c * 8 + srow;         // 0..127 (row & 7 == srow)
      const unsigned short* srcA = A + (size_t)(m0 + row) * K + kt + soct;
      GLOAD_LDS16(srcA, Al + c * 1024);
      const unsigned short* srcB = Bt + (size_t)(n0 + row) * K + kt + soct;
      GLOAD_LDS16(srcB, Bl + c * 1024);
    }
    __syncthreads();
#pragma unroll
    for (int kk = 0; kk < 2; ++kk) {
      const int roct = ((kk * 4 + g) ^ rx) << 4;  // swizzled read octet (bytes)
      s16x8 af[4], bfr[4];
#pragma unroll
      for (int mi = 0; mi < 4; ++mi) {
        int row = wr * 64 + mi * 16 + l15;
        af[mi] = *(const s16x8*)(Al + row * 128 + roct);
      }
#pragma unroll
      for (int ni = 0; ni < 4; ++ni) {
        int row = wc * 64 + ni * 16 + l15;
        bfr[ni] = *(const s16x8*)(Bl + row * 128 + roct);
      }
#pragma unroll
      for (int mi = 0; mi < 4; ++mi)
#pragma unroll
        for (int ni = 0; ni < 4; ++ni)
          acc[mi][ni] = MFMA32(af[mi], bfr[ni], acc[mi][ni]);
    }
  }
  // epilogue: D layout col=lane&15, row=(lane>>4)*4+r
#pragma unroll
  for (int ni = 0; ni < 4; ++ni) {
    int col = n0 + wc * 64 + ni * 16 + l15;
    float bv = bias[col];
#pragma unroll
    for (int mi = 0; mi < 4; ++mi) {
      int row = m0 + wr * 64 + mi * 16 + g * 4;
#pragma unroll
      for (int r = 0; r < 4; ++r) {
        float v = acc[mi][ni][r] + bv;
        if (OUTF32)
          ((float*)Cout)[(size_t)(row + r) * N + col] = v;
        else
          ((unsigned short*)Cout)[(size_t)(row + r) * N + col] = f2bf(v);
      }
    }
  }
}

// ---------------------------------------------------------------- attention
// QBLK=128: 4 waves x 32 q/wave (two 16-q fragments A/B). grid (8, B*H) =
// 512 blocks = 2 independent 4-wave blocks/CU (2 waves/SIMD from DIFFERENT
// blocks -> stall interleave preserved). Block bx: tiles {15-bx, bx}, 34
// balanced kv-iters. K-frag and V-frag LDS reads shared between A and B
// (halves the LDS-pipe load per unit compute -- r12 showed LDS-issue-bound).
// K: octet-XOR swizzle; V^T: stride-76 padded scatter; ones-MFMA row-sum;
// max3 tree; T13 defer-max; 2-deep reg prefetch (flat 34-iter schedule).
#define VT_STR 76
#define VT_BLK 1232
__global__ __launch_bounds__(256, 2) void attn_kernel(
    const unsigned short* __restrict__ qkv, unsigned short* __restrict__ yatt) {
  __shared__ char lds[18048];  // K 8192 + Vt 9856; ylds[64][130]=16640 aliases
  const int bx = blockIdx.x;          // 0..7
  const int bh = blockIdx.y;
  const int b = bh >> 4, h = bh & 15;
  const int w = threadIdx.x >> 6;
  const int lane = threadIdx.x & 63;
  const int l15 = lane & 15, g = lane >> 4;

  const size_t rowstride = 3 * D_;  // 3072 elems per token row
  const unsigned short* Qb = qkv + (size_t)b * T_ * rowstride + h * HD_;
  const unsigned short* Kb = Qb + D_;
  const unsigned short* Vb = Qb + 2 * D_;

  char* Klds = lds;
  unsigned short* Vt = (unsigned short*)(lds + 8192);  // [4 blk][16 d][76 key]

  const int krow0 = (w * 2 + 0) * 8 + (lane >> 3);
  const int krow1 = (w * 2 + 1) * 8 + (lane >> 3);
  const int u = lane & 7;
  const int vkey = w * 16 + (lane >> 2);
  const int vdb = lane & 3;
  const float SC = 0.18033688011112042f;  // log2(e)/sqrt(64)
  const s16x4 onesf = {(short)0x3F80, (short)0x3F80, (short)0x3F80, (short)0x3F80};

  const int qtA_t = 15 - bx;          // first (long) tile
  const int nA = 2 * qtA_t + 2;       // its kv-iter count; total = 34

  // 2-deep prefetch slots (named; rotated by mov)
  s16x8 kc0, kc1, vc0, vc1;
  s16x8 kn0, kn1, vn0, vn1;

  auto ld = [&](int kt, s16x8& a, s16x8& b2, s16x8& c, s16x8& d2) {
    const unsigned short* kb = Kb + (size_t)(kt * 64) * rowstride;
    a = *(const s16x8*)(kb + (size_t)krow0 * rowstride + u * 8);
    b2 = *(const s16x8*)(kb + (size_t)krow1 * rowstride + u * 8);
    const unsigned short* vs = Vb + (size_t)(kt * 64 + vkey) * rowstride + vdb * 16;
    c = *(const s16x8*)(vs);
    d2 = *(const s16x8*)(vs + 8);
  };

  ld(0, kc0, kc1, vc0, vc1);
  ld(1, kn0, kn1, vn0, vn1);
  int f = 0;                          // flat kv-iter counter, 0..33

#pragma unroll 1
  for (int ti = 0; ti < 2; ++ti) {
    const int qt = ti ? bx : qtA_t;
    const int ntk = 2 * qt + 2;
    const int base = qt * 128 + w * 32;  // wave's first q row
    // Q fragments, SC pre-folded; group A rows base+0..15, group B +16..31
    s16x8 qfA0, qfA1, qfB0, qfB1;
    {
      const unsigned short* qa = Qb + (size_t)(base + l15) * rowstride;
      const unsigned short* qb = Qb + (size_t)(base + 16 + l15) * rowstride;
      s16x8 a0 = *(const s16x8*)(qa + g * 8);
      s16x8 a1 = *(const s16x8*)(qa + 32 + g * 8);
      s16x8 b0 = *(const s16x8*)(qb + g * 8);
      s16x8 b1 = *(const s16x8*)(qb + 32 + g * 8);
#pragma unroll
      for (int j = 0; j < 8; ++j) {
        qfA0[j] = (short)f2bf(bf2f((unsigned short)a0[j]) * SC);
        qfA1[j] = (short)f2bf(bf2f((unsigned short)a1[j]) * SC);
        qfB0[j] = (short)f2bf(bf2f((unsigned short)b0[j]) * SC);
        qfB1[j] = (short)f2bf(bf2f((unsigned short)b1[j]) * SC);
      }
    }
    float mA = -1e30f, mB = -1e30f;
    f32x4 accA[4] = {}, accB[4] = {};
    f32x4 accSA = {}, accSB = {};

#pragma unroll 1
    for (int kt = 0; kt < ntk; ++kt) {
      __syncthreads();
      // K: octet-XOR-swizzled write
      *(s16x8*)(Klds + krow0 * 128 + ((u ^ (krow0 & 7)) << 4)) = kc0;
      *(s16x8*)(Klds + krow1 * 128 + ((u ^ (krow1 & 7)) << 4)) = kc1;
      // V^T: block-padded scatter
#pragma unroll
      for (int j = 0; j < 8; ++j) {
        Vt[vdb * VT_BLK + j * VT_STR + vkey] = (unsigned short)vc0[j];
        Vt[vdb * VT_BLK + (8 + j) * VT_STR + vkey] = (unsigned short)vc1[j];
      }
      __syncthreads();
      // rotate slots and issue flat f+2 load
      kc0 = kn0; kc1 = kn1; vc0 = vn0; vc1 = vn1;
      {
        int f2 = f + 2;
        if (f2 < 34) {
          int kt2 = (f2 < nA) ? f2 : f2 - nA;
          ld(kt2, kn0, kn1, vn0, vn1);
        }
      }
      ++f;

      // wave guard (base%32==0 -> A-active iff B-active)
      if (kt * 64 > base + 31) continue;

      // QK^T: shared K-frag reads feed both q-groups
      float tvA[16], tvB[16];
      __builtin_amdgcn_s_setprio(1);
#pragma unroll
      for (int kk = 0; kk < 4; ++kk) {
        int key = kk * 16 + l15;
        const s16x8 kf0 = *(const s16x8*)(Klds + key * 128 + ((g ^ (key & 7)) << 4));
        const s16x8 kf1 = *(const s16x8*)(Klds + key * 128 + (((4 + g) ^ (key & 7)) << 4));
        f32x4 sA = {}, sB = {};
        sA = MFMA32(kf0, qfA0, sA);
        sA = MFMA32(kf1, qfA1, sA);
        sB = MFMA32(kf0, qfB0, sB);
        sB = MFMA32(kf1, qfB1, sB);
#pragma unroll
        for (int r = 0; r < 4; ++r) { tvA[kk * 4 + r] = sA[r]; tvB[kk * 4 + r] = sB[r]; }
      }
      __builtin_amdgcn_s_setprio(0);
      if (kt * 64 + 63 > base) {  // diagonal region: causal mask both groups
        int qA = base + l15, qB = base + 16 + l15;
#pragma unroll
        for (int kk = 0; kk < 4; ++kk)
#pragma unroll
          for (int r = 0; r < 4; ++r) {
            int key = kt * 64 + kk * 16 + g * 4 + r;
            if (key > qA) tvA[kk * 4 + r] = -1e30f;
            if (key > qB) tvB[kk * 4 + r] = -1e30f;
          }
      }
      s16x4 pbA[4], pbB[4];
      // ---- softmax group A
      {
        float a0 = fmaxf(fmaxf(tvA[0], tvA[1]), tvA[2]);
        float a1 = fmaxf(fmaxf(tvA[3], tvA[4]), tvA[5]);
        float a2 = fmaxf(fmaxf(tvA[6], tvA[7]), tvA[8]);
        float a3 = fmaxf(fmaxf(tvA[9], tvA[10]), tvA[11]);
        float a4 = fmaxf(fmaxf(tvA[12], tvA[13]), tvA[14]);
        float tm = fmaxf(fmaxf(fmaxf(a0, a1), a2), fmaxf(fmaxf(a3, a4), tvA[15]));
        tm = fmaxf(tm, __shfl_xor(tm, 16));
        tm = fmaxf(tm, __shfl_xor(tm, 32));
        if (!__all(tm - mA <= 8.0f)) {
          float mn = fmaxf(mA, tm);
          float corr = exp2f(mA - mn);
          mA = mn;
#pragma unroll
          for (int i = 0; i < 4; ++i) {
            accA[i][0] *= corr; accA[i][1] *= corr;
            accA[i][2] *= corr; accA[i][3] *= corr;
          }
          accSA[0] *= corr; accSA[1] *= corr; accSA[2] *= corr; accSA[3] *= corr;
        }
#pragma unroll
        for (int kk = 0; kk < 4; ++kk) {
          float p0 = exp2f(tvA[kk * 4 + 0] - mA), p1 = exp2f(tvA[kk * 4 + 1] - mA);
          float p2 = exp2f(tvA[kk * 4 + 2] - mA), p3 = exp2f(tvA[kk * 4 + 3] - mA);
          u32x2 pk;
          pk[0] = __builtin_amdgcn_perm(__builtin_bit_cast(unsigned, p1),
                                        __builtin_bit_cast(unsigned, p0), 0x07060302u);
          pk[1] = __builtin_amdgcn_perm(__builtin_bit_cast(unsigned, p3),
                                        __builtin_bit_cast(unsigned, p2), 0x07060302u);
          pbA[kk] = __builtin_bit_cast(s16x4, pk);
        }
      }
      // ---- softmax group B
      {
        float a0 = fmaxf(fmaxf(tvB[0], tvB[1]), tvB[2]);
        float a1 = fmaxf(fmaxf(tvB[3], tvB[4]), tvB[5]);
        float a2 = fmaxf(fmaxf(tvB[6], tvB[7]), tvB[8]);
        float a3 = fmaxf(fmaxf(tvB[9], tvB[10]), tvB[11]);
        float a4 = fmaxf(fmaxf(tvB[12], tvB[13]), tvB[14]);
        float tm = fmaxf(fmaxf(fmaxf(a0, a1), a2), fmaxf(fmaxf(a3, a4), tvB[15]));
        tm = fmaxf(tm, __shfl_xor(tm, 16));
        tm = fmaxf(tm, __shfl_xor(tm, 32));
        if (!__all(tm - mB <= 8.0f)) {
          float mn = fmaxf(mB, tm);
          float corr = exp2f(mB - mn);
          mB = mn;
#pragma unroll
          for (int i = 0; i < 4; ++i) {
            accB[i][0] *= corr; accB[i][1] *= corr;
            accB[i][2] *= corr; accB[i][3] *= corr;
          }
          accSB[0] *= corr; accSB[1] *= corr; accSB[2] *= corr; accSB[3] *= corr;
        }
#pragma unroll
        for (int kk = 0; kk < 4; ++kk) {
          float p0 = exp2f(tvB[kk * 4 + 0] - mB), p1 = exp2f(tvB[kk * 4 + 1] - mB);
          float p2 = exp2f(tvB[kk * 4 + 2] - mB), p3 = exp2f(tvB[kk * 4 + 3] - mB);
          u32x2 pk;
          pk[0] = __builtin_amdgcn_perm(__builtin_bit_cast(unsigned, p1),
                                        __builtin_bit_cast(unsigned, p0), 0x07060302u);
          pk[1] = __builtin_amdgcn_perm(__builtin_bit_cast(unsigned, p3),
                                        __builtin_bit_cast(unsigned, p2), 0x07060302u);
          pbB[kk] = __builtin_bit_cast(s16x4, pk);
        }
      }
      // PV: shared V-frag reads feed both q-groups; ones-MFMA row-sums
      __builtin_amdgcn_s_setprio(1);
#pragma unroll
      for (int kk = 0; kk < 4; ++kk) {
#pragma unroll
        for (int db = 0; db < 4; ++db) {
          s16x4 vf = *(const s16x4*)(Vt + db * VT_BLK + l15 * VT_STR + kk * 16 + g * 4);
          accA[db] = MFMA16(vf, pbA[kk], accA[db]);
          accB[db] = MFMA16(vf, pbB[kk], accB[db]);
        }
        accSA = MFMA16(onesf, pbA[kk], accSA);
        accSB = MFMA16(onesf, pbB[kk], accSB);
      }
      __builtin_amdgcn_s_setprio(0);
    }

    // epilogue: denominators + transpose y^T -> y via ylds[64][130]
    float invA = 1.0f / accSA[0];
    float invB = 1.0f / accSB[0];
    __syncthreads();
    unsigned short* ylds = (unsigned short*)lds;  // [64 d][130]
#pragma unroll
    for (int db = 0; db < 4; ++db)
#pragma unroll
      for (int r = 0; r < 4; ++r) {
        int d = db * 16 + g * 4 + r;
        ylds[d * 130 + w * 32 + l15] = f2bf(accA[db][r] * invA);
        ylds[d * 130 + w * 32 + 16 + l15] = f2bf(accB[db][r] * invB);
      }
    __syncthreads();
    {
      int qq = threadIdx.x >> 1;         // 0..127
      int dc = (threadIdx.x & 1) * 32;   // 0 or 32
      s16x8 o0, o1, o2, o3;
#pragma unroll
      for (int j = 0; j < 8; ++j) {
        o0[j] = (short)ylds[(dc + j) * 130 + qq];
        o1[j] = (short)ylds[(dc + 8 + j) * 130 + qq];
        o2[j] = (short)ylds[(dc + 16 + j) * 130 + qq];
        o3[j] = (short)ylds[(dc + 24 + j) * 130 + qq];
      }
      unsigned short* dst =
          yatt + (size_t)(b * T_ + qt * 128 + qq) * D_ + h * HD_ + dc;
      *(s16x8*)(dst) = o0;
      *(s16x8*)(dst + 8) = o1;
      *(s16x8*)(dst + 16) = o2;
      *(s16x8*)(dst + 24) = o3;
    }
  }
}

// ---------------------------------------------------------------- launcher
extern "C" void kernel_launch(void* const* d_in, const int* in_sizes, int n_in,
                              void* d_out, int out_size, void* d_ws, size_t ws_size,
                              hipStream_t stream) {
  const float* x     = (const float*)d_in[0];
  const float* Wqkv  = (const float*)d_in[1];
  const float* bqkv  = (const float*)d_in[2];
  const float* Wproj = (const float*)d_in[3];
  const float* bproj = (const float*)d_in[4];
  float* out = (float*)d_out;

  // workspace layout (bf16 buffers), 72 MiB total; yb aliases xb (dead after gemm<0>)
  unsigned short* xb   = (unsigned short*)d_ws;              // [8192][1024]
  unsigned short* Wqb  = xb + (size_t)8192 * 1024;           // [3072][1024] (W_qkv^T)
  unsigned short* Wpb  = Wqb + (size_t)3072 * 1024;          // [1024][1024] (W_proj^T)
  unsigned short* qkvb = Wpb + (size_t)1024 * 1024;          // [8192][3072]
  unsigned short* yb   = xb;                                 // alias: x dead after gemm<0>

  convert_x_kernel<<<dim3(4096), dim3(256), 0, stream>>>(x, xb, 8192 * 1024 / 8);
  transpose_w_kernel<<<dim3(96, 32), dim3(256), 0, stream>>>(Wqkv, Wqb, 1024, 3072);
  transpose_w_kernel<<<dim3(32, 32), dim3(256), 0, stream>>>(Wproj, Wpb, 1024, 1024);
  gemm_kernel<0><<<dim3(24, 64), dim3(256), 0, stream>>>(xb, Wqb, bqkv, qkvb, 8192, 3072, 1024);
  attn_kernel<<<dim3(8, 64), dim3(256), 0, stream>>>(qkvb, yb);
  gemm_kernel<1><<<dim3(8, 64), dim3(256), 0, stream>>>(yb, Wpb, bproj, out, 8192, 1024, 1024);
}